// Round 11
// baseline (9817.021 us; speedup 1.0000x reference)
//
#include <hip/hip_runtime.h>
#include <cstdint>
#include <cstddef>

// ============================================================================
// PointerNet: encoder LSTM (B=512,S=256,D=2,H=256) + autoregressive pointer
// decode with jax.random.categorical (threefry2x32 partitionable, key 42).
// Output: int32 indices [512][256], trajectory-exact vs JAX reference.
//
// R15 = R14 (gate-split encoder + u-split decoder) with the encoder exchange
// rebuilt on the PROVEN tagged-word pattern. R14 was neutral (9350 vs 9294):
// gate-split halved encoder weight bytes but its sync (4 barriers + a
// tid0-only flag round trip parking the whole block) ate the savings
// (VALUBusy 48->37%). R15 encoder step: 2 barriers, no flag —
//   S_B | waves 8-15: compute partner-half gate sums from red2, publish as
//         2 tagged u64 each (tag 0xD0+t | float bits)       [RT issued early]
//       | P2 threads (tid<512): own-half sum, spin own 2 gx words, gates,
//         c,h, encK4 store, tagged-h publish+spin (0xC0+t, R14 pattern)
//   S_C
// Same bits exchanged as R14 -> bit-identical trajectory (R14 absmax 0).
// Workspace unchanged at 134MiB: tagged GX = 2MiB @0x100000 (reclaimed dead
// space); decoder AMX aliases GX words 0..7 per (g,H) (encoder-only region,
// disjoint tag spaces 0xA5.. vs 0xD0..). Decoder verbatim R13/R14.
// ============================================================================

typedef float v4f __attribute__((ext_vector_type(4)));
typedef float v2f __attribute__((ext_vector_type(2)));
typedef unsigned long long u64;

#define WS_HX_OFF     0x000000u          // [128 g][2 H][512] u64 = 1 MiB (tagged h)
#define WS_GX_OFF     0x100000u          // [128 g][2 H][1024] u64 = 2 MiB (tagged gates; words 0..7 = decoder AMX)
#define WS_SYNC_BYTES 0x300000u
#define WS_ENCW2_OFF  0x300000u          // [2 H][256 k][256 u][2 g] f32 = 1 MiB
#define WS_DECWI4_OFF 0x400000u
#define WS_DECWH4_OFF 0x500000u
#define WS_ENCK4_OFF  0x600000u          // [512 b][64 u4][256 s][4] f32
#define WS_NEEDED     ((size_t)WS_ENCK4_OFF + (size_t)512 * 64 * 256 * 16)

__device__ __forceinline__ unsigned rotl32(unsigned x, int r) {
  return (x << r) | (x >> (32 - r));
}
__device__ __forceinline__ float sigm(float x) { return 1.f / (1.f + expf(-x)); }

__device__ __forceinline__ u64 pk(unsigned tag, unsigned payload) {
  return ((u64)tag << 32) | (u64)payload;
}
// device-scope atomic read (resolves at coherence point; no stale L1/L2)
__device__ __forceinline__ unsigned spinrd(u64* p, unsigned tag) {
  u64 v = atomicAdd(p, 0ull);
  while ((unsigned)(v >> 32) != tag) {
    __builtin_amdgcn_s_sleep(2);
    v = atomicAdd(p, 0ull);
  }
  return (unsigned)v;
}

// Threefry-2x32, 20 rounds (jax._src.prng schedule) — verified exact R1-R14.
__device__ __forceinline__ void tf2(unsigned k0, unsigned k1,
                                    unsigned& x0, unsigned& x1) {
  const unsigned k2 = k0 ^ k1 ^ 0x1BD11BDAu;
  x0 += k0; x1 += k1;
  x0 += x1; x1 = rotl32(x1, 13); x1 ^= x0;
  x0 += x1; x1 = rotl32(x1, 15); x1 ^= x0;
  x0 += x1; x1 = rotl32(x1, 26); x1 ^= x0;
  x0 += x1; x1 = rotl32(x1,  6); x1 ^= x0;
  x0 += k1; x1 += k2 + 1u;
  x0 += x1; x1 = rotl32(x1, 17); x1 ^= x0;
  x0 += x1; x1 = rotl32(x1, 29); x1 ^= x0;
  x0 += x1; x1 = rotl32(x1, 16); x1 ^= x0;
  x0 += x1; x1 = rotl32(x1, 24); x1 ^= x0;
  x0 += k2; x1 += k0 + 2u;
  x0 += x1; x1 = rotl32(x1, 13); x1 ^= x0;
  x0 += x1; x1 = rotl32(x1, 15); x1 ^= x0;
  x0 += x1; x1 = rotl32(x1, 26); x1 ^= x0;
  x0 += x1; x1 = rotl32(x1,  6); x1 ^= x0;
  x0 += k0; x1 += k1 + 3u;
  x0 += x1; x1 = rotl32(x1, 17); x1 ^= x0;
  x0 += x1; x1 = rotl32(x1, 29); x1 ^= x0;
  x0 += x1; x1 = rotl32(x1, 16); x1 ^= x0;
  x0 += x1; x1 = rotl32(x1, 24); x1 ^= x0;
  x0 += k1; x1 += k2 + 4u;
  x0 += x1; x1 = rotl32(x1, 13); x1 ^= x0;
  x0 += x1; x1 = rotl32(x1, 15); x1 ^= x0;
  x0 += x1; x1 = rotl32(x1, 26); x1 ^= x0;
  x0 += x1; x1 = rotl32(x1,  6); x1 ^= x0;
  x0 += k2; x1 += k0 + 5u;
}

// Repack: decoder W -> [k][u][4g] float4; encoder Wh -> per-half [k][u][2g].
__global__ void repack_k(const float* __restrict__ eWh,
                         const float* __restrict__ dWi,
                         const float* __restrict__ dWh,
                         float* __restrict__ ws) {
  float* encW2 = (float*)((char*)ws + WS_ENCW2_OFF);
  float* decWi4 = (float*)((char*)ws + WS_DECWI4_OFF);
  float* decWh4 = (float*)((char*)ws + WS_DECWH4_OFF);
  const int n = blockIdx.x * blockDim.x + threadIdx.x;   // 65536 = 256k x 256u
  if (n >= 65536) return;
  const int k = n >> 8, u = n & 255;
#pragma unroll
  for (int g = 0; g < 4; ++g) {
    const int src = ((g << 8) + u) * 256 + k;
    decWi4[(n << 2) + g] = dWi[src];
    decWh4[(n << 2) + g] = dWh[src];
    encW2[(((g >> 1) << 16) + n) * 2 + (g & 1)] = eWh[src];
  }
}

__global__ void __launch_bounds__(1024)
ptrnet_kernel(const float* __restrict__ inp,    // [512][256][2]
              const float* __restrict__ eWi,    // [1024][2]
              const float* __restrict__ eBi, const float* __restrict__ eBh,
              const float* __restrict__ dBi, const float* __restrict__ dBh,
              int* __restrict__ out,            // [512][256]
              float* __restrict__ ws) {
  const int tid  = threadIdx.x;
  const int wave = tid >> 6, l = tid & 63;
  const int kq   = wave >> 2;               // 16-wave (kq x u-slice) partition
  const int uw   = wave & 3;
  const int uP   = (uw << 6) | l;
  const int k4b  = kq << 4;

  const int g    = blockIdx.x & 127;        // pair id
  const int H    = blockIdx.x >> 7;         // half: 0 = gates(i,f)+u[0,128)
  const int b0   = g << 2;
  const int ubase = H << 7;
  const int pbase = ubase ^ 128;
  const int sbase = H << 7;

  // split-P2 identity (encoder P2, decoder P2): thread tid<512 -> (bD,uD)
  const int isP2 = tid < 512;
  const int bD = tid >> 7;
  const int uL = tid & 127;
  const int uD = ubase | uL;
  const int bGD = b0 + bD;

  const v2f* encW2o = (const v2f*)((char*)ws + WS_ENCW2_OFF) + (H << 16);
  const v4f* decWi4 = (const v4f*)((char*)ws + WS_DECWI4_OFF);
  const v4f* decWh4 = (const v4f*)((char*)ws + WS_DECWH4_OFF);
  v4f* encK4 = (v4f*)((char*)ws + WS_ENCK4_OFF);

  u64* hxAll  = (u64*)((char*)ws + WS_HX_OFF);
  u64* hxMe   = hxAll + (size_t)g * 1024 + (size_t)H * 512;
  u64* hxYo   = hxAll + (size_t)g * 1024 + (size_t)(1 - H) * 512;
  u64* gxAll  = (u64*)((char*)ws + WS_GX_OFF);
  u64* gxMe   = gxAll + ((size_t)g * 2 + (size_t)H) * 1024;
  u64* gxYo   = gxAll + ((size_t)g * 2 + (size_t)(1 - H)) * 1024;
  u64* amxMe  = gxMe;                        // decoder-only alias (words 0..7)
  u64* amxYo  = gxYo;

  __shared__ __align__(16) float hsF[2][1024];   // h dbuf: [buf][b*256+u]
  __shared__ __align__(16) v4f dinV[256];        // dec_in [b][64 k4]
  __shared__ __align__(16) v4f red[17][256];     // partials (v2f-aliased in enc)
  __shared__ unsigned char maskC[4][128];        // own s-half mask
  __shared__ float partV[4][2];
  __shared__ int   partI[4][2];
  __shared__ float oVs[4]; __shared__ int oIs[4];
  __shared__ float eVs[4]; __shared__ int eIs[4];
  v2f* red2 = (v2f*)&red[0][0];                  // [16 rows][256 u] v2f

  // ---- encoder activation constants (keyed by uD; P2 threads only) ----
  const int uB = isP2 ? uD : 0;
  const float ebi_ = eBi[uB] + eBh[uB];
  const float ebf_ = eBi[256 + uB] + eBh[256 + uB];
  const float ebg_ = eBi[512 + uB] + eBh[512 + uB];
  const float ebo_ = eBi[768 + uB] + eBh[768 + uB];
  const float wxi0 = eWi[2 * uB], wxi1 = eWi[2 * uB + 1];
  const float wxf0 = eWi[2 * (256 + uB)], wxf1 = eWi[2 * (256 + uB) + 1];
  const float wxg0 = eWi[2 * (512 + uB)], wxg1 = eWi[2 * (512 + uB) + 1];
  const float wxo0 = eWi[2 * (768 + uB)], wxo1 = eWi[2 * (768 + uB) + 1];

  hsF[0][tid] = 0.f;
  __syncthreads();

  float cD = 0.f;       // cell state for (bGD, uD) — register-resident throughout
  int p = 0;

  // ---------------- encoder: 256 steps, gate-split across the pair ----------
  for (int t = 0; t < 256; ++t) {
    // P1: own gate-pair partials over FULL u (16 waves, v2f, R10 kk order)
    {
      v2f a0 = (v2f)0.f, a1 = (v2f)0.f, a2 = (v2f)0.f, a3 = (v2f)0.f;
      const v2f* Wp = encW2o + uP;
      const v4f* hq = (const v4f*)&hsF[p][0];
#pragma unroll 2
      for (int kk = 0; kk < 16; ++kk) {
        const int k4 = k4b + kk;
        const v2f w0 = Wp[(k4 * 4 + 0) << 8];
        const v2f w1 = Wp[(k4 * 4 + 1) << 8];
        const v2f w2 = Wp[(k4 * 4 + 2) << 8];
        const v2f w3 = Wp[(k4 * 4 + 3) << 8];
        const v4f h0 = hq[k4];
        const v4f h1 = hq[64 + k4];
        const v4f h2 = hq[128 + k4];
        const v4f h3 = hq[192 + k4];
        a0 += w0 * h0.x + w1 * h0.y + w2 * h0.z + w3 * h0.w;
        a1 += w0 * h1.x + w1 * h1.y + w2 * h1.z + w3 * h1.w;
        a2 += w0 * h2.x + w1 * h2.y + w2 * h2.z + w3 * h2.w;
        a3 += w0 * h3.x + w1 * h3.y + w2 * h3.z + w3 * h3.w;
      }
      red2[(((kq << 2) | 0) << 8) + uP] = a0;
      red2[(((kq << 2) | 1) << 8) + uP] = a1;
      red2[(((kq << 2) | 2) << 8) + uP] = a2;
      red2[(((kq << 2) | 3) << 8) + uP] = a3;
    }
    __syncthreads();                              // S_B: partials ready

    const unsigned tagG = 0xD0000000u + (unsigned)t;
    if (!isP2) {
      // waves 8-15: compute + publish partner-half gate sums (RT starts now)
      const int ix = tid - 512;                   // 0..511
      const int bP = ix >> 7, uLp = ix & 127;
      const int upub = pbase | uLp;
      v2f gx = red2[(bP << 8) + upub];
      gx += red2[((4 + bP) << 8) + upub];
      gx += red2[((8 + bP) << 8) + upub];
      gx += red2[((12 + bP) << 8) + upub];
      atomicExch(&gxMe[(ix << 1) + 0], pk(tagG, __float_as_uint(gx.x)));
      atomicExch(&gxMe[(ix << 1) + 1], pk(tagG, __float_as_uint(gx.y)));
    } else {
      // P2 threads: own-half sum, spin partner gate pair, gates -> c,h
      v2f own = red2[(bD << 8) + uD];
      own += red2[((4 + bD) << 8) + uD];
      own += red2[((8 + bD) << 8) + uD];
      own += red2[((12 + bD) << 8) + uD];
      const int ix = tid;                         // (bD<<7)|uL
      const float ox = __uint_as_float(spinrd(&gxYo[(ix << 1) + 0], tagG));
      const float oy = __uint_as_float(spinrd(&gxYo[(ix << 1) + 1], tagG));
      const float gvI = H ? ox : own.x;
      const float gvF = H ? oy : own.y;
      const float gvG = H ? own.x : ox;
      const float gvO = H ? own.y : oy;
      const float2 xv = *(const float2*)(inp + (((bGD) << 8) + t) * 2);
      const float ai = gvI + ebi_ + wxi0 * xv.x + wxi1 * xv.y;
      const float af = gvF + ebf_ + wxf0 * xv.x + wxf1 * xv.y;
      const float ag = gvG + ebg_ + wxg0 * xv.x + wxg1 * xv.y;
      const float ao = gvO + ebo_ + wxo0 * xv.x + wxo1 * xv.y;
      const float iv = sigm(ai), fv = sigm(af), gva = tanhf(ag), ov = sigm(ao);
      cD = fv * cD + iv * gva;
      const float hn = ov * tanhf(cD);
      hsF[p ^ 1][(bD << 8) | uD] = hn;
      ((float*)encK4)[(((bGD << 6) + (uD >> 2)) << 10) + (t << 2) + (uD & 3)] = hn;
      atomicExch(&hxMe[(bD << 7) | uL], pk(0xC0000001u + (unsigned)t, __float_as_uint(hn)));
      const unsigned pw2 = spinrd(&hxYo[(bD << 7) | uL], 0xC0000001u + (unsigned)t);
      hsF[p ^ 1][(bD << 8) | pbase | uL] = __uint_as_float(pw2);
    }
    __syncthreads();                              // S_C: full h_{t+1} in LDS
    p ^= 1;
  }

  // ---------------- decoder (verbatim R13/R14; cD already split-owned) ------
  float dbi2 = 0.f, dbf2 = 0.f, dbg2 = 0.f, dbo2 = 0.f;
  if (isP2) {
    dbi2 = dBi[uD] + dBh[uD];
    dbf2 = dBi[256 + uD] + dBh[256 + uD];
    dbg2 = dBi[512 + uD] + dBh[512 + uD];
    dbo2 = dBi[768 + uD] + dBh[768 + uD];
  }
  // attn identity (valid for wave >= 8)
  const int aw  = wave - 8;
  const int bAt = aw >> 1;
  const int sL  = ((aw & 1) << 6) | l;
  const int sG  = sbase | sL;
  const int bGt = b0 + bAt;
  if (wave >= 8) maskC[bAt][sL] = 0;
  // Wh/Wi identity (valid for wave < 8)
  const int kqD  = wave >> 1;
  const int k4bD = kqD << 4;
  const int uPD  = ubase | ((wave & 1) << 6) | l;
  const float NEG_INF = __int_as_float((int)0xff800000);
  __syncthreads();

  // ---- prologue: LSTM step 0 (din=0, Wi exact-0 skipped). Wh redundant
  //      16-wave full-u (identical values in both blocks); P2 split. ----
  {
    v4f a0 = (v4f)0.f, a1 = (v4f)0.f, a2 = (v4f)0.f, a3 = (v4f)0.f;
    const v4f* Wh = decWh4 + uP;
    const v4f* hq = (const v4f*)&hsF[p][0];
#pragma unroll 2
    for (int kk = 0; kk < 16; ++kk) {
      const int k4 = k4b + kk;
      const v4f w0 = Wh[(k4 * 4 + 0) << 8];
      const v4f w1 = Wh[(k4 * 4 + 1) << 8];
      const v4f w2 = Wh[(k4 * 4 + 2) << 8];
      const v4f w3 = Wh[(k4 * 4 + 3) << 8];
      const v4f h0 = hq[k4];
      const v4f h1 = hq[64 + k4];
      const v4f h2 = hq[128 + k4];
      const v4f h3 = hq[192 + k4];
      a0 += w0 * h0.x + w1 * h0.y + w2 * h0.z + w3 * h0.w;
      a1 += w0 * h1.x + w1 * h1.y + w2 * h1.z + w3 * h1.w;
      a2 += w0 * h2.x + w1 * h2.y + w2 * h2.z + w3 * h2.w;
      a3 += w0 * h3.x + w1 * h3.y + w2 * h3.z + w3 * h3.w;
    }
    red[(kq << 2) | 0][uP] = a0;
    red[(kq << 2) | 1][uP] = a1;
    red[(kq << 2) | 2][uP] = a2;
    red[(kq << 2) | 3][uP] = a3;
    __syncthreads();
    if (isP2) {
      const v4f gv = red[bD][uD] + red[4 + bD][uD] + red[8 + bD][uD] + red[12 + bD][uD];
      const float iv = sigm(gv.x + dbi2), fv = sigm(gv.y + dbf2);
      const float gva = tanhf(gv.z + dbg2), ov = sigm(gv.w + dbo2);
      cD = fv * cD + iv * gva;
      const float hn = ov * tanhf(cD);
      hsF[p ^ 1][(bD << 8) | uD] = hn;
      atomicExch(&hxMe[(bD << 7) | uL], pk(0xA5000000u, __float_as_uint(hn)));
      const unsigned pw = spinrd(&hxYo[(bD << 7) | uL], 0xA5000000u);
      hsF[p ^ 1][(bD << 8) | pbase | uL] = __uint_as_float(pw);
    }
    __syncthreads();
    p ^= 1;                                   // hsF[p] = full h_0
  }

#define WINNER(B, WI) { float _wv = oVs[B]; int _wi = oIs[B];                 \
    const float _ev = eVs[B]; const int _ei = eIs[B];                         \
    if (_ev > _wv || (_ev == _wv && _ei < _wi)) { _wi = _ei; }                \
    WI = _wi; }

  for (int t = 0; t < 256; ++t) {
    const unsigned tagA = 0xA5000001u + 2u * (unsigned)t;
    const unsigned tagH = 0xA5000002u + 2u * (unsigned)t;
    const v4f* hq = (const v4f*)&hsF[p][0];

    // ==== phase X: waves 0-7 Wh·h_t (u-half) ∥ waves 8-15 attention(t) ====
    if (wave < 8) {
      v4f a0 = (v4f)0.f, a1 = (v4f)0.f, a2 = (v4f)0.f, a3 = (v4f)0.f;
      const v4f* Wh = decWh4 + uPD;
#pragma unroll 2
      for (int kk = 0; kk < 16; ++kk) {
        const int k4 = k4bD + kk;
        const v4f w0 = Wh[(k4 * 4 + 0) << 8];
        const v4f w1 = Wh[(k4 * 4 + 1) << 8];
        const v4f w2 = Wh[(k4 * 4 + 2) << 8];
        const v4f w3 = Wh[(k4 * 4 + 3) << 8];
        const v4f h0 = hq[k4];
        const v4f h1 = hq[64 + k4];
        const v4f h2 = hq[128 + k4];
        const v4f h3 = hq[192 + k4];
        a0 += w0 * h0.x + w1 * h0.y + w2 * h0.z + w3 * h0.w;
        a1 += w0 * h1.x + w1 * h1.y + w2 * h1.z + w3 * h1.w;
        a2 += w0 * h2.x + w1 * h2.y + w2 * h2.z + w3 * h2.w;
        a3 += w0 * h3.x + w1 * h3.y + w2 * h3.z + w3 * h3.w;
      }
      red[(kqD << 2) | 0][uPD] = a0;
      red[(kqD << 2) | 1][uPD] = a1;
      red[(kqD << 2) | 2][uPD] = a2;
      red[(kqD << 2) | 3][uPD] = a3;
    } else {
      const int masked = maskC[bAt][sL];
      float sc = 0.f;
      if (!masked) {
        const v4f* E = encK4 + (bGt << 14) + sG;
        const v4f* hq2 = hq + (bAt << 6);
#pragma unroll 4
        for (int k4 = 0; k4 < 64; ++k4) {
          const v4f ev = E[k4 << 8];
          const v4f hv = hq2[k4];
          sc += ev.x * hv.x + ev.y * hv.y + ev.z * hv.z + ev.w * hv.w;
        }
      }
      unsigned bits;
      {
        unsigned kk0 = 0u, kk1 = (unsigned)t;
        tf2(0u, 42u, kk0, kk1);
        unsigned y0 = 0u, y1 = (unsigned)((bGt << 8) + sG);
        tf2(kk0, kk1, y0, y1);
        bits = y0 ^ y1;
      }
      const float fr = __uint_as_float((bits >> 9) | 0x3f800000u) - 1.0f;
      const float uu = (fr > 0.f) ? fr : 1.17549435e-38f;
      const float gum = -logf(-logf(uu));
      float bv = masked ? NEG_INF : (sc + gum);
      int bi = sG;
#pragma unroll
      for (int off = 32; off; off >>= 1) {
        const float ov2 = __shfl_xor(bv, off, 64);
        const int oi2 = __shfl_xor(bi, off, 64);
        if (ov2 > bv || (ov2 == bv && oi2 < bi)) { bv = ov2; bi = oi2; }
      }
      if (l == 0) { partV[bAt][aw & 1] = bv; partI[bAt][aw & 1] = bi; }
    }
    __syncthreads();                          // S1: red-Wh + partials ready

    // ==== local combine + publish (tid 0-3); spin partner (tid 64-71) ====
    if (tid < 4) {
      float v0 = partV[tid][0]; int i0 = partI[tid][0];
      const float v1 = partV[tid][1];
      if (v1 > v0) { v0 = v1; i0 = partI[tid][1]; }   // strict >: lower s kept
      oVs[tid] = v0; oIs[tid] = i0;
      atomicExch(&amxMe[tid * 2 + 0], pk(tagA, __float_as_uint(v0)));
      atomicExch(&amxMe[tid * 2 + 1], pk(tagA, (unsigned)i0));
    }
    if (tid >= 64 && tid < 72) {
      const int j = tid - 64;                 // b*2 + {val,idx}
      const unsigned pw = spinrd(&amxYo[j], tagA);
      if (j & 1) eIs[j >> 1] = (int)pw;
      else       eVs[j >> 1] = __uint_as_float(pw);
    }
    __syncthreads();                          // S2: both halves' results ready

    // ==== winner, mask, out, din staging ====
    if (wave >= 8) {
      int wi; WINNER(bAt, wi);
      if (sG == wi) maskC[bAt][sL] = 1;
    }
    if (H == 0 && tid < 4) {
      int wi; WINNER(tid, wi);
      out[((b0 + tid) << 8) + t] = wi;
    }
    if (tid < 256) {
      const int bb = tid >> 6, k4s = tid & 63;
      int wi; WINNER(bb, wi);
      dinV[tid] = encK4[((((b0 + bb) << 6) | k4s) << 8) + wi];
    }
    __syncthreads();                          // S3: din/mask ready

    if (t == 255) break;                      // last index emitted

    // ==== Wi·din sweep (waves 0-7, continue chain from red — lossless) ====
    if (wave < 8) {
      v4f a0 = red[(kqD << 2) | 0][uPD];
      v4f a1 = red[(kqD << 2) | 1][uPD];
      v4f a2 = red[(kqD << 2) | 2][uPD];
      v4f a3 = red[(kqD << 2) | 3][uPD];
      const v4f* Wi = decWi4 + uPD;
#pragma unroll 2
      for (int kk = 0; kk < 16; ++kk) {
        const int k4 = k4bD + kk;
        const v4f w0 = Wi[(k4 * 4 + 0) << 8];
        const v4f w1 = Wi[(k4 * 4 + 1) << 8];
        const v4f w2 = Wi[(k4 * 4 + 2) << 8];
        const v4f w3 = Wi[(k4 * 4 + 3) << 8];
        const v4f d0 = dinV[k4];
        const v4f d1 = dinV[64 + k4];
        const v4f d2 = dinV[128 + k4];
        const v4f d3 = dinV[192 + k4];
        a0 += w0 * d0.x + w1 * d0.y + w2 * d0.z + w3 * d0.w;
        a1 += w0 * d1.x + w1 * d1.y + w2 * d1.z + w3 * d1.w;
        a2 += w0 * d2.x + w1 * d2.y + w2 * d2.z + w3 * d2.w;
        a3 += w0 * d3.x + w1 * d3.y + w2 * d3.z + w3 * d3.w;
      }
      red[(kqD << 2) | 0][uPD] = a0;
      red[(kqD << 2) | 1][uPD] = a1;
      red[(kqD << 2) | 2][uPD] = a2;
      red[(kqD << 2) | 3][uPD] = a3;
    }
    __syncthreads();                          // S4: full partials ready

    // ==== P2 (split) -> h_{t+1}; publish + fetch partner half ====
    if (isP2) {
      const v4f gv = red[bD][uD] + red[4 + bD][uD] + red[8 + bD][uD] + red[12 + bD][uD];
      const float iv = sigm(gv.x + dbi2), fv = sigm(gv.y + dbf2);
      const float gva = tanhf(gv.z + dbg2), ov = sigm(gv.w + dbo2);
      cD = fv * cD + iv * gva;
      const float hn = ov * tanhf(cD);
      hsF[p ^ 1][(bD << 8) | uD] = hn;
      atomicExch(&hxMe[(bD << 7) | uL], pk(tagH, __float_as_uint(hn)));
      const unsigned pw = spinrd(&hxYo[(bD << 7) | uL], tagH);
      hsF[p ^ 1][(bD << 8) | pbase | uL] = __uint_as_float(pw);
    }
    __syncthreads();                          // S5: full h_{t+1} ready
    p ^= 1;
  }
#undef WINNER
}

extern "C" void kernel_launch(void* const* d_in, const int* in_sizes, int n_in,
                              void* d_out, int out_size, void* d_ws, size_t ws_size,
                              hipStream_t stream) {
  (void)in_sizes; (void)n_in; (void)out_size;
  if (ws_size < WS_NEEDED) return;   // need 134 MiB scratch

  const float* inp = (const float*)d_in[0];
  const float* eWi = (const float*)d_in[1];
  const float* eWh = (const float*)d_in[2];
  const float* eBi = (const float*)d_in[3];
  const float* eBh = (const float*)d_in[4];
  const float* dWi = (const float*)d_in[5];
  const float* dWh = (const float*)d_in[6];
  const float* dBi = (const float*)d_in[7];
  const float* dBh = (const float*)d_in[8];
  int* out = (int*)d_out;
  float* wsf = (float*)d_ws;

  // zero the sync region every launch: fresh tags, no ABA across graph replays
  hipMemsetAsync((char*)d_ws, 0, WS_SYNC_BYTES, stream);
  hipLaunchKernelGGL(repack_k, dim3(256), dim3(256), 0, stream, eWh, dWi, dWh, wsf);
  hipLaunchKernelGGL(ptrnet_kernel, dim3(256), dim3(1024), 0, stream,
                     inp, eWi, eBi, eBh, dBi, dBh, out, wsf);
}

// Round 12
// 9812.334 us; speedup vs baseline: 1.0005x; 1.0005x over previous
//
#include <hip/hip_runtime.h>
#include <cstdint>
#include <cstddef>

// ============================================================================
// PointerNet: encoder LSTM (B=512,S=256,D=2,H=256) + autoregressive pointer
// decode with jax.random.categorical (threefry2x32 partitionable, key 42).
// Output: int32 indices [512][256], trajectory-exact vs JAX reference.
//
// R16 = R13 (best verified, 9294us) + deeper load-pipeline unrolls.
// R14/R15 post-mortem: gate-split encoder fails both ways (flag sync eats it,
// R14; per-thread tagged sync eats it, R15) -> the encoder is NOT weight-
// stream-bound. Re-derivation: enc ~22.8us/step vs 7.4us stream + 3.4us VALU
// floors -> dominant cost is EXPOSED L2 LATENCY (only ~8 loads in flight at
// unroll 2, 32 CUs queue per XCD-L2). Fix: unroll 4 on all weight sweeps
// (encoder P1, decoder prologue, phaseX Wh, Wi), unroll 8 on attention k4 —
// pure scheduling change, FMA chain order identical -> exact trajectory.
//
// Structure (R13): 256 blocks, pair (g, g+128) on same 4 batches; decoder
// u-split (weights/CU halved), s-split attention; tagged-u64 atomic exchange
// (argmax + h) — proven absmax 0. Encoder redundant per pair (R10-exact).
// ============================================================================

typedef float v4f __attribute__((ext_vector_type(4)));
typedef unsigned long long u64;

#define WS_HX_OFF     0u                 // [128 g][2 H][512] u64 = 1 MB
#define WS_AMX_OFF    (1u << 20)         // [128 g][2 H][8] u64 = 16 KB
#define WS_SYNC_BYTES 0x110000u
#define WS_ENCW4_OFF  (2u << 20)         // [256 k][256 u][4 g] f32
#define WS_DECWI4_OFF (3u << 20)
#define WS_DECWH4_OFF (4u << 20)
#define WS_ENCK4_OFF  (5u << 20)         // [512 b][64 u4][256 s][4] f32
#define WS_NEEDED     ((size_t)(5u << 20) + (size_t)512 * 64 * 256 * 16)

__device__ __forceinline__ unsigned rotl32(unsigned x, int r) {
  return (x << r) | (x >> (32 - r));
}
__device__ __forceinline__ float sigm(float x) { return 1.f / (1.f + expf(-x)); }

__device__ __forceinline__ u64 pk(unsigned tag, unsigned payload) {
  return ((u64)tag << 32) | (u64)payload;
}
// device-scope atomic read (resolves at coherence point; no stale L1/L2)
__device__ __forceinline__ unsigned spinrd(u64* p, unsigned tag) {
  u64 v = atomicAdd(p, 0ull);
  while ((unsigned)(v >> 32) != tag) {
    __builtin_amdgcn_s_sleep(2);
    v = atomicAdd(p, 0ull);
  }
  return (unsigned)v;
}

// Threefry-2x32, 20 rounds (jax._src.prng schedule) — verified exact R1-R15.
__device__ __forceinline__ void tf2(unsigned k0, unsigned k1,
                                    unsigned& x0, unsigned& x1) {
  const unsigned k2 = k0 ^ k1 ^ 0x1BD11BDAu;
  x0 += k0; x1 += k1;
  x0 += x1; x1 = rotl32(x1, 13); x1 ^= x0;
  x0 += x1; x1 = rotl32(x1, 15); x1 ^= x0;
  x0 += x1; x1 = rotl32(x1, 26); x1 ^= x0;
  x0 += x1; x1 = rotl32(x1,  6); x1 ^= x0;
  x0 += k1; x1 += k2 + 1u;
  x0 += x1; x1 = rotl32(x1, 17); x1 ^= x0;
  x0 += x1; x1 = rotl32(x1, 29); x1 ^= x0;
  x0 += x1; x1 = rotl32(x1, 16); x1 ^= x0;
  x0 += x1; x1 = rotl32(x1, 24); x1 ^= x0;
  x0 += k2; x1 += k0 + 2u;
  x0 += x1; x1 = rotl32(x1, 13); x1 ^= x0;
  x0 += x1; x1 = rotl32(x1, 15); x1 ^= x0;
  x0 += x1; x1 = rotl32(x1, 26); x1 ^= x0;
  x0 += x1; x1 = rotl32(x1,  6); x1 ^= x0;
  x0 += k0; x1 += k1 + 3u;
  x0 += x1; x1 = rotl32(x1, 17); x1 ^= x0;
  x0 += x1; x1 = rotl32(x1, 29); x1 ^= x0;
  x0 += x1; x1 = rotl32(x1, 16); x1 ^= x0;
  x0 += x1; x1 = rotl32(x1, 24); x1 ^= x0;
  x0 += k1; x1 += k2 + 4u;
  x0 += x1; x1 = rotl32(x1, 13); x1 ^= x0;
  x0 += x1; x1 = rotl32(x1, 15); x1 ^= x0;
  x0 += x1; x1 = rotl32(x1, 26); x1 ^= x0;
  x0 += x1; x1 = rotl32(x1,  6); x1 ^= x0;
  x0 += k2; x1 += k0 + 5u;
}

// Repack W [1024 rows][256 k] row-major -> [k][u][gate] (float4 per (k,u)).
__global__ void repack_k(const float* __restrict__ eWh,
                         const float* __restrict__ dWi,
                         const float* __restrict__ dWh,
                         float* __restrict__ ws) {
  float* encW4 = (float*)((char*)ws + WS_ENCW4_OFF);
  float* decWi4 = (float*)((char*)ws + WS_DECWI4_OFF);
  float* decWh4 = (float*)((char*)ws + WS_DECWH4_OFF);
  const int n = blockIdx.x * blockDim.x + threadIdx.x;   // 65536 = 256k x 256u
  if (n >= 65536) return;
  const int k = n >> 8, u = n & 255;
#pragma unroll
  for (int g = 0; g < 4; ++g) {
    const int src = ((g << 8) + u) * 256 + k;
    const int dst = (n << 2) + g;
    encW4[dst] = eWh[src];
    decWi4[dst] = dWi[src];
    decWh4[dst] = dWh[src];
  }
}

__global__ void __launch_bounds__(1024)
ptrnet_kernel(const float* __restrict__ inp,    // [512][256][2]
              const float* __restrict__ eWi,    // [1024][2]
              const float* __restrict__ eBi, const float* __restrict__ eBh,
              const float* __restrict__ dBi, const float* __restrict__ dBh,
              int* __restrict__ out,            // [512][256]
              float* __restrict__ ws) {
  const int tid  = threadIdx.x;
  const int wave = tid >> 6, l = tid & 63;
  const int kq   = wave >> 2;               // encoder/prologue partition
  const int uw   = wave & 3;
  const int uP   = (uw << 6) | l;
  const int k4b  = kq << 4;
  const int bA   = tid >> 8;                // encoder P2 partition
  const int uA   = tid & 255;

  const int g    = blockIdx.x & 127;        // pair id
  const int H    = blockIdx.x >> 7;         // half: 0 = lo, 1 = hi
  const int b0   = g << 2;
  const int bG   = b0 + bA;
  const int ubase = H << 7;                 // owned u range [ubase, ubase+128)
  const int pbase = ubase ^ 128;            // partner's u base
  const int sbase = H << 7;                 // owned s range

  const v4f* encW4  = (const v4f*)((char*)ws + WS_ENCW4_OFF);
  const v4f* decWi4 = (const v4f*)((char*)ws + WS_DECWI4_OFF);
  const v4f* decWh4 = (const v4f*)((char*)ws + WS_DECWH4_OFF);
  v4f* encK4 = (v4f*)((char*)ws + WS_ENCK4_OFF);

  u64* hxAll  = (u64*)((char*)ws + WS_HX_OFF);
  u64* hxMe   = hxAll + (size_t)g * 1024 + (size_t)H * 512;
  u64* hxYo   = hxAll + (size_t)g * 1024 + (size_t)(1 - H) * 512;
  u64* amxAll = (u64*)((char*)ws + WS_AMX_OFF);
  u64* amxMe  = amxAll + (size_t)g * 16 + (size_t)H * 8;
  u64* amxYo  = amxAll + (size_t)g * 16 + (size_t)(1 - H) * 8;

  __shared__ __align__(16) float hsF[2][1024];   // h dbuf: [buf][b*256+u]
  __shared__ __align__(16) v4f dinV[256];        // dec_in [b][64 k4]
  __shared__ __align__(16) v4f red[17][256];     // partials; row 16 = LDS pad
  __shared__ unsigned char maskC[4][128];        // own s-half mask
  __shared__ float partV[4][2];
  __shared__ int   partI[4][2];
  __shared__ float oVs[4]; __shared__ int oIs[4];   // own half combined
  __shared__ float eVs[4]; __shared__ int eIs[4];   // partner half

  // ---- encoder activation constants (keyed by uA) ----
  const float ebi_ = eBi[uA] + eBh[uA];
  const float ebf_ = eBi[256 + uA] + eBh[256 + uA];
  const float ebg_ = eBi[512 + uA] + eBh[512 + uA];
  const float ebo_ = eBi[768 + uA] + eBh[768 + uA];
  const float wxi0 = eWi[2 * uA], wxi1 = eWi[2 * uA + 1];
  const float wxf0 = eWi[2 * (256 + uA)], wxf1 = eWi[2 * (256 + uA) + 1];
  const float wxg0 = eWi[2 * (512 + uA)], wxg1 = eWi[2 * (512 + uA) + 1];
  const float wxo0 = eWi[2 * (768 + uA)], wxo1 = eWi[2 * (768 + uA) + 1];

  hsF[0][tid] = 0.f;
  __syncthreads();

  float c = 0.f;
  int p = 0;

  // ---------------- encoder: 256 steps (R10-exact, redundant per pair) ------
  for (int t = 0; t < 256; ++t) {
    v4f a0 = (v4f)0.f, a1 = (v4f)0.f, a2 = (v4f)0.f, a3 = (v4f)0.f;
    const v4f* Wp = encW4 + uP;
    const v4f* hq = (const v4f*)&hsF[p][0];
#pragma unroll 4
    for (int kk = 0; kk < 16; ++kk) {
      const int k4 = k4b + kk;
      const v4f w0 = Wp[(k4 * 4 + 0) << 8];
      const v4f w1 = Wp[(k4 * 4 + 1) << 8];
      const v4f w2 = Wp[(k4 * 4 + 2) << 8];
      const v4f w3 = Wp[(k4 * 4 + 3) << 8];
      const v4f h0 = hq[k4];
      const v4f h1 = hq[64 + k4];
      const v4f h2 = hq[128 + k4];
      const v4f h3 = hq[192 + k4];
      a0 += w0 * h0.x + w1 * h0.y + w2 * h0.z + w3 * h0.w;
      a1 += w0 * h1.x + w1 * h1.y + w2 * h1.z + w3 * h1.w;
      a2 += w0 * h2.x + w1 * h2.y + w2 * h2.z + w3 * h2.w;
      a3 += w0 * h3.x + w1 * h3.y + w2 * h3.z + w3 * h3.w;
    }
    red[(kq << 2) | 0][uP] = a0;
    red[(kq << 2) | 1][uP] = a1;
    red[(kq << 2) | 2][uP] = a2;
    red[(kq << 2) | 3][uP] = a3;
    __syncthreads();
    const v4f gv = red[bA][uA] + red[4 + bA][uA] + red[8 + bA][uA] + red[12 + bA][uA];
    const float2 xv = *(const float2*)(inp + (((bG) << 8) + t) * 2);
    const float ai = gv.x + ebi_ + wxi0 * xv.x + wxi1 * xv.y;
    const float af = gv.y + ebf_ + wxf0 * xv.x + wxf1 * xv.y;
    const float ag = gv.z + ebg_ + wxg0 * xv.x + wxg1 * xv.y;
    const float ao = gv.w + ebo_ + wxo0 * xv.x + wxo1 * xv.y;
    const float iv = sigm(ai), fv = sigm(af), gva = tanhf(ag), ov = sigm(ao);
    c = fv * c + iv * gva;
    const float hn = ov * tanhf(c);
    hsF[p ^ 1][(bA << 8) | uA] = hn;
    ((float*)encK4)[(((bG << 6) + (uA >> 2)) << 10) + (t << 2) + (uA & 3)] = hn;
    __syncthreads();
    p ^= 1;
  }

  // ---------------- decoder setup: c handoff to split mapping ----------------
  float* creg = (float*)&red[0][0];
  creg[(bA << 8) | uA] = c;
  const int isP2 = tid < 512;
  const int bD = tid >> 7;                  // 0..3   (valid if isP2)
  const int uL = tid & 127;
  const int uD = ubase | uL;                // owned global u
  __syncthreads();
  float cD = 0.f, dbi2 = 0.f, dbf2 = 0.f, dbg2 = 0.f, dbo2 = 0.f;
  if (isP2) {
    cD = creg[(bD << 8) | uD];
    dbi2 = dBi[uD] + dBh[uD];
    dbf2 = dBi[256 + uD] + dBh[256 + uD];
    dbg2 = dBi[512 + uD] + dBh[512 + uD];
    dbo2 = dBi[768 + uD] + dBh[768 + uD];
  }
  // attn identity (valid for wave >= 8)
  const int aw  = wave - 8;
  const int bAt = aw >> 1;
  const int sL  = ((aw & 1) << 6) | l;
  const int sG  = sbase | sL;
  const int bGt = b0 + bAt;
  if (wave >= 8) maskC[bAt][sL] = 0;
  // Wh/Wi identity (valid for wave < 8)
  const int kqD  = wave >> 1;
  const int k4bD = kqD << 4;
  const int uPD  = ubase | ((wave & 1) << 6) | l;
  const float NEG_INF = __int_as_float((int)0xff800000);
  __syncthreads();                           // creg consumed; red free

  // ---- prologue: LSTM step 0 (din=0, Wi exact-0 skipped). Wh redundant
  //      16-wave full-u (identical values in both blocks); P2 split. ----
  {
    v4f a0 = (v4f)0.f, a1 = (v4f)0.f, a2 = (v4f)0.f, a3 = (v4f)0.f;
    const v4f* Wh = decWh4 + uP;
    const v4f* hq = (const v4f*)&hsF[p][0];
#pragma unroll 4
    for (int kk = 0; kk < 16; ++kk) {
      const int k4 = k4b + kk;
      const v4f w0 = Wh[(k4 * 4 + 0) << 8];
      const v4f w1 = Wh[(k4 * 4 + 1) << 8];
      const v4f w2 = Wh[(k4 * 4 + 2) << 8];
      const v4f w3 = Wh[(k4 * 4 + 3) << 8];
      const v4f h0 = hq[k4];
      const v4f h1 = hq[64 + k4];
      const v4f h2 = hq[128 + k4];
      const v4f h3 = hq[192 + k4];
      a0 += w0 * h0.x + w1 * h0.y + w2 * h0.z + w3 * h0.w;
      a1 += w0 * h1.x + w1 * h1.y + w2 * h1.z + w3 * h1.w;
      a2 += w0 * h2.x + w1 * h2.y + w2 * h2.z + w3 * h2.w;
      a3 += w0 * h3.x + w1 * h3.y + w2 * h3.z + w3 * h3.w;
    }
    red[(kq << 2) | 0][uP] = a0;
    red[(kq << 2) | 1][uP] = a1;
    red[(kq << 2) | 2][uP] = a2;
    red[(kq << 2) | 3][uP] = a3;
    __syncthreads();
    if (isP2) {
      const v4f gv = red[bD][uD] + red[4 + bD][uD] + red[8 + bD][uD] + red[12 + bD][uD];
      const float iv = sigm(gv.x + dbi2), fv = sigm(gv.y + dbf2);
      const float gva = tanhf(gv.z + dbg2), ov = sigm(gv.w + dbo2);
      cD = fv * cD + iv * gva;
      const float hn = ov * tanhf(cD);
      hsF[p ^ 1][(bD << 8) | uD] = hn;
      atomicExch(&hxMe[(bD << 7) | uL], pk(0xA5000000u, __float_as_uint(hn)));
      const unsigned pw = spinrd(&hxYo[(bD << 7) | uL], 0xA5000000u);
      hsF[p ^ 1][(bD << 8) | pbase | uL] = __uint_as_float(pw);
    }
    __syncthreads();
    p ^= 1;                                   // hsF[p] = full h_0
  }

#define WINNER(B, WI) { float _wv = oVs[B]; int _wi = oIs[B];                 \
    const float _ev = eVs[B]; const int _ei = eIs[B];                         \
    if (_ev > _wv || (_ev == _wv && _ei < _wi)) { _wi = _ei; }                \
    WI = _wi; }

  for (int t = 0; t < 256; ++t) {
    const unsigned tagA = 0xA5000001u + 2u * (unsigned)t;
    const unsigned tagH = 0xA5000002u + 2u * (unsigned)t;
    const v4f* hq = (const v4f*)&hsF[p][0];

    // ==== phase X: waves 0-7 Wh·h_t (u-half) ∥ waves 8-15 attention(t) ====
    if (wave < 8) {
      v4f a0 = (v4f)0.f, a1 = (v4f)0.f, a2 = (v4f)0.f, a3 = (v4f)0.f;
      const v4f* Wh = decWh4 + uPD;
#pragma unroll 4
      for (int kk = 0; kk < 16; ++kk) {
        const int k4 = k4bD + kk;
        const v4f w0 = Wh[(k4 * 4 + 0) << 8];
        const v4f w1 = Wh[(k4 * 4 + 1) << 8];
        const v4f w2 = Wh[(k4 * 4 + 2) << 8];
        const v4f w3 = Wh[(k4 * 4 + 3) << 8];
        const v4f h0 = hq[k4];
        const v4f h1 = hq[64 + k4];
        const v4f h2 = hq[128 + k4];
        const v4f h3 = hq[192 + k4];
        a0 += w0 * h0.x + w1 * h0.y + w2 * h0.z + w3 * h0.w;
        a1 += w0 * h1.x + w1 * h1.y + w2 * h1.z + w3 * h1.w;
        a2 += w0 * h2.x + w1 * h2.y + w2 * h2.z + w3 * h2.w;
        a3 += w0 * h3.x + w1 * h3.y + w2 * h3.z + w3 * h3.w;
      }
      red[(kqD << 2) | 0][uPD] = a0;
      red[(kqD << 2) | 1][uPD] = a1;
      red[(kqD << 2) | 2][uPD] = a2;
      red[(kqD << 2) | 3][uPD] = a3;
    } else {
      const int masked = maskC[bAt][sL];
      float sc = 0.f;
      if (!masked) {
        const v4f* E = encK4 + (bGt << 14) + sG;
        const v4f* hq2 = hq + (bAt << 6);
#pragma unroll 8
        for (int k4 = 0; k4 < 64; ++k4) {
          const v4f ev = E[k4 << 8];
          const v4f hv = hq2[k4];
          sc += ev.x * hv.x + ev.y * hv.y + ev.z * hv.z + ev.w * hv.w;
        }
      }
      unsigned bits;
      {
        unsigned kk0 = 0u, kk1 = (unsigned)t;
        tf2(0u, 42u, kk0, kk1);
        unsigned y0 = 0u, y1 = (unsigned)((bGt << 8) + sG);
        tf2(kk0, kk1, y0, y1);
        bits = y0 ^ y1;
      }
      const float fr = __uint_as_float((bits >> 9) | 0x3f800000u) - 1.0f;
      const float uu = (fr > 0.f) ? fr : 1.17549435e-38f;
      const float gum = -logf(-logf(uu));
      float bv = masked ? NEG_INF : (sc + gum);
      int bi = sG;
#pragma unroll
      for (int off = 32; off; off >>= 1) {
        const float ov2 = __shfl_xor(bv, off, 64);
        const int oi2 = __shfl_xor(bi, off, 64);
        if (ov2 > bv || (ov2 == bv && oi2 < bi)) { bv = ov2; bi = oi2; }
      }
      if (l == 0) { partV[bAt][aw & 1] = bv; partI[bAt][aw & 1] = bi; }
    }
    __syncthreads();                          // S1: red-Wh + partials ready

    // ==== local combine + publish (tid 0-3); spin partner (tid 64-71) ====
    if (tid < 4) {
      float v0 = partV[tid][0]; int i0 = partI[tid][0];
      const float v1 = partV[tid][1];
      if (v1 > v0) { v0 = v1; i0 = partI[tid][1]; }   // strict >: lower s kept
      oVs[tid] = v0; oIs[tid] = i0;
      atomicExch(&amxMe[tid * 2 + 0], pk(tagA, __float_as_uint(v0)));
      atomicExch(&amxMe[tid * 2 + 1], pk(tagA, (unsigned)i0));
    }
    if (tid >= 64 && tid < 72) {
      const int j = tid - 64;                 // b*2 + {val,idx}
      const unsigned pw = spinrd(&amxYo[j], tagA);
      if (j & 1) eIs[j >> 1] = (int)pw;
      else       eVs[j >> 1] = __uint_as_float(pw);
    }
    __syncthreads();                          // S2: both halves' results ready

    // ==== winner, mask, out, din staging ====
    if (wave >= 8) {
      int wi; WINNER(bAt, wi);
      if (sG == wi) maskC[bAt][sL] = 1;
    }
    if (H == 0 && tid < 4) {
      int wi; WINNER(tid, wi);
      out[((b0 + tid) << 8) + t] = wi;
    }
    if (tid < 256) {
      const int bb = tid >> 6, k4s = tid & 63;
      int wi; WINNER(bb, wi);
      dinV[tid] = encK4[((((b0 + bb) << 6) | k4s) << 8) + wi];
    }
    __syncthreads();                          // S3: din/mask ready

    if (t == 255) break;                      // last index emitted

    // ==== Wi·din sweep (waves 0-7, continue chain from red — lossless) ====
    if (wave < 8) {
      v4f a0 = red[(kqD << 2) | 0][uPD];
      v4f a1 = red[(kqD << 2) | 1][uPD];
      v4f a2 = red[(kqD << 2) | 2][uPD];
      v4f a3 = red[(kqD << 2) | 3][uPD];
      const v4f* Wi = decWi4 + uPD;
#pragma unroll 4
      for (int kk = 0; kk < 16; ++kk) {
        const int k4 = k4bD + kk;
        const v4f w0 = Wi[(k4 * 4 + 0) << 8];
        const v4f w1 = Wi[(k4 * 4 + 1) << 8];
        const v4f w2 = Wi[(k4 * 4 + 2) << 8];
        const v4f w3 = Wi[(k4 * 4 + 3) << 8];
        const v4f d0 = dinV[k4];
        const v4f d1 = dinV[64 + k4];
        const v4f d2 = dinV[128 + k4];
        const v4f d3 = dinV[192 + k4];
        a0 += w0 * d0.x + w1 * d0.y + w2 * d0.z + w3 * d0.w;
        a1 += w0 * d1.x + w1 * d1.y + w2 * d1.z + w3 * d1.w;
        a2 += w0 * d2.x + w1 * d2.y + w2 * d2.z + w3 * d2.w;
        a3 += w0 * d3.x + w1 * d3.y + w2 * d3.z + w3 * d3.w;
      }
      red[(kqD << 2) | 0][uPD] = a0;
      red[(kqD << 2) | 1][uPD] = a1;
      red[(kqD << 2) | 2][uPD] = a2;
      red[(kqD << 2) | 3][uPD] = a3;
    }
    __syncthreads();                          // S4: full partials ready

    // ==== P2 (split) -> h_{t+1}; publish + fetch partner half ====
    if (isP2) {
      const v4f gv = red[bD][uD] + red[4 + bD][uD] + red[8 + bD][uD] + red[12 + bD][uD];
      const float iv = sigm(gv.x + dbi2), fv = sigm(gv.y + dbf2);
      const float gva = tanhf(gv.z + dbg2), ov = sigm(gv.w + dbo2);
      cD = fv * cD + iv * gva;
      const float hn = ov * tanhf(cD);
      hsF[p ^ 1][(bD << 8) | uD] = hn;
      atomicExch(&hxMe[(bD << 7) | uL], pk(tagH, __float_as_uint(hn)));
      const unsigned pw = spinrd(&hxYo[(bD << 7) | uL], tagH);
      hsF[p ^ 1][(bD << 8) | pbase | uL] = __uint_as_float(pw);
    }
    __syncthreads();                          // S5: full h_{t+1} ready
    p ^= 1;
  }
#undef WINNER
}

extern "C" void kernel_launch(void* const* d_in, const int* in_sizes, int n_in,
                              void* d_out, int out_size, void* d_ws, size_t ws_size,
                              hipStream_t stream) {
  (void)in_sizes; (void)n_in; (void)out_size;
  if (ws_size < WS_NEEDED) return;   // need ~139 MB scratch

  const float* inp = (const float*)d_in[0];
  const float* eWi = (const float*)d_in[1];
  const float* eWh = (const float*)d_in[2];
  const float* eBi = (const float*)d_in[3];
  const float* eBh = (const float*)d_in[4];
  const float* dWi = (const float*)d_in[5];
  const float* dWh = (const float*)d_in[6];
  const float* dBi = (const float*)d_in[7];
  const float* dBh = (const float*)d_in[8];
  int* out = (int*)d_out;
  float* wsf = (float*)d_ws;

  // zero the sync region every launch: fresh tags, no ABA across graph replays
  hipMemsetAsync((char*)d_ws + WS_HX_OFF, 0, WS_SYNC_BYTES, stream);
  hipLaunchKernelGGL(repack_k, dim3(256), dim3(256), 0, stream, eWh, dWi, dWh, wsf);
  hipLaunchKernelGGL(ptrnet_kernel, dim3(256), dim3(1024), 0, stream,
                     inp, eWi, eBi, eBh, dBi, dBh, out, wsf);
}

// Round 13
// 9497.995 us; speedup vs baseline: 1.0336x; 1.0331x over previous
//
#include <hip/hip_runtime.h>
#include <cstdint>
#include <cstddef>

// ============================================================================
// PointerNet: encoder LSTM (B=512,S=256,D=2,H=256) + autoregressive pointer
// decode with jax.random.categorical (threefry2x32 partitionable, key 42).
// Output: int32 indices [512][256], trajectory-exact vs JAX reference.
//
// R17 = R13 (best verified, 9294us) + two bit-exact scheduling fixes:
//  1. EARLY argmax publish: attention wave lane0 publishes its per-wave
//     partial (packed u64: tag9|val32|idx8) immediately after the shfl
//     argmax, INSIDE phase X — before barrier S1. R13 published after S1,
//     i.e. after the slowest (Wh) wave, leaving the cross-block RT fully
//     exposed (~2us/step). Now the word is in flight during the Wh tail.
//     Winner = lexicographic fold (max val, min idx on tie) over
//     {own-combined, partner-wave0, partner-wave1} — order-independent,
//     bit-identical result to R13's 2-way fold.
//  2. Wi sweep GATE-SPLIT over all 16 waves (R13 left waves 8-15 idle
//     here): the 4 gate chains in each v4f accumulator are lane-wise
//     independent; thread (kq,u,gate-pair) runs the identical per-gate
//     FLOP sequence on a v2f — same bits, same L2 lines, 2x waves for
//     latency hiding of the 0.5MB Wi stream.
// R16 post-mortem: unroll4/8 neutral-negative -> reverted to R13's unrolls.
// Structure (R13): 256 blocks, pair (g, g+128) on same 4 batches; decoder
// u-split + s-split attention; tagged-u64 atomic exchange; encoder
// redundant per pair (R10-exact). All proven absmax 0.
// ============================================================================

typedef float v4f __attribute__((ext_vector_type(4)));
typedef float v2f __attribute__((ext_vector_type(2)));
typedef unsigned long long u64;

#define WS_HX_OFF     0u                 // [128 g][2 H][512] u64 = 1 MB
#define WS_AMX_OFF    (1u << 20)         // [128 g][2 H][8] u64 = 16 KB
#define WS_SYNC_BYTES 0x110000u
#define WS_ENCW4_OFF  (2u << 20)         // [256 k][256 u][4 g] f32
#define WS_DECWI4_OFF (3u << 20)
#define WS_DECWH4_OFF (4u << 20)
#define WS_ENCK4_OFF  (5u << 20)         // [512 b][64 u4][256 s][4] f32
#define WS_NEEDED     ((size_t)(5u << 20) + (size_t)512 * 64 * 256 * 16)

__device__ __forceinline__ unsigned rotl32(unsigned x, int r) {
  return (x << r) | (x >> (32 - r));
}
__device__ __forceinline__ float sigm(float x) { return 1.f / (1.f + expf(-x)); }

__device__ __forceinline__ u64 pk(unsigned tag, unsigned payload) {
  return ((u64)tag << 32) | (u64)payload;
}
// argmax partial: [tag9:24][val:32][idx:8]; tag = t+1 (1..256, never 0)
__device__ __forceinline__ u64 pk49(unsigned tag9, float v, int idx) {
  return ((u64)tag9 << 40) | ((u64)__float_as_uint(v) << 8) | (u64)(idx & 0xFF);
}
// device-scope atomic read (resolves at coherence point; no stale L1/L2)
__device__ __forceinline__ unsigned spinrd(u64* p, unsigned tag) {
  u64 v = atomicAdd(p, 0ull);
  while ((unsigned)(v >> 32) != tag) {
    __builtin_amdgcn_s_sleep(2);
    v = atomicAdd(p, 0ull);
  }
  return (unsigned)v;
}
__device__ __forceinline__ u64 spinrd49(u64* p, unsigned tag9) {
  u64 v = atomicAdd(p, 0ull);
  while ((unsigned)(v >> 40) != tag9) {
    __builtin_amdgcn_s_sleep(2);
    v = atomicAdd(p, 0ull);
  }
  return v;
}

// Threefry-2x32, 20 rounds (jax._src.prng schedule) — verified exact R1-R16.
__device__ __forceinline__ void tf2(unsigned k0, unsigned k1,
                                    unsigned& x0, unsigned& x1) {
  const unsigned k2 = k0 ^ k1 ^ 0x1BD11BDAu;
  x0 += k0; x1 += k1;
  x0 += x1; x1 = rotl32(x1, 13); x1 ^= x0;
  x0 += x1; x1 = rotl32(x1, 15); x1 ^= x0;
  x0 += x1; x1 = rotl32(x1, 26); x1 ^= x0;
  x0 += x1; x1 = rotl32(x1,  6); x1 ^= x0;
  x0 += k1; x1 += k2 + 1u;
  x0 += x1; x1 = rotl32(x1, 17); x1 ^= x0;
  x0 += x1; x1 = rotl32(x1, 29); x1 ^= x0;
  x0 += x1; x1 = rotl32(x1, 16); x1 ^= x0;
  x0 += x1; x1 = rotl32(x1, 24); x1 ^= x0;
  x0 += k2; x1 += k0 + 2u;
  x0 += x1; x1 = rotl32(x1, 13); x1 ^= x0;
  x0 += x1; x1 = rotl32(x1, 15); x1 ^= x0;
  x0 += x1; x1 = rotl32(x1, 26); x1 ^= x0;
  x0 += x1; x1 = rotl32(x1,  6); x1 ^= x0;
  x0 += k0; x1 += k1 + 3u;
  x0 += x1; x1 = rotl32(x1, 17); x1 ^= x0;
  x0 += x1; x1 = rotl32(x1, 29); x1 ^= x0;
  x0 += x1; x1 = rotl32(x1, 16); x1 ^= x0;
  x0 += x1; x1 = rotl32(x1, 24); x1 ^= x0;
  x0 += k1; x1 += k2 + 4u;
  x0 += x1; x1 = rotl32(x1, 13); x1 ^= x0;
  x0 += x1; x1 = rotl32(x1, 15); x1 ^= x0;
  x0 += x1; x1 = rotl32(x1, 26); x1 ^= x0;
  x0 += x1; x1 = rotl32(x1,  6); x1 ^= x0;
  x0 += k2; x1 += k0 + 5u;
}

// Repack W [1024 rows][256 k] row-major -> [k][u][gate] (float4 per (k,u)).
__global__ void repack_k(const float* __restrict__ eWh,
                         const float* __restrict__ dWi,
                         const float* __restrict__ dWh,
                         float* __restrict__ ws) {
  float* encW4 = (float*)((char*)ws + WS_ENCW4_OFF);
  float* decWi4 = (float*)((char*)ws + WS_DECWI4_OFF);
  float* decWh4 = (float*)((char*)ws + WS_DECWH4_OFF);
  const int n = blockIdx.x * blockDim.x + threadIdx.x;   // 65536 = 256k x 256u
  if (n >= 65536) return;
  const int k = n >> 8, u = n & 255;
#pragma unroll
  for (int g = 0; g < 4; ++g) {
    const int src = ((g << 8) + u) * 256 + k;
    const int dst = (n << 2) + g;
    encW4[dst] = eWh[src];
    decWi4[dst] = dWi[src];
    decWh4[dst] = dWh[src];
  }
}

__global__ void __launch_bounds__(1024)
ptrnet_kernel(const float* __restrict__ inp,    // [512][256][2]
              const float* __restrict__ eWi,    // [1024][2]
              const float* __restrict__ eBi, const float* __restrict__ eBh,
              const float* __restrict__ dBi, const float* __restrict__ dBh,
              int* __restrict__ out,            // [512][256]
              float* __restrict__ ws) {
  const int tid  = threadIdx.x;
  const int wave = tid >> 6, l = tid & 63;
  const int kq   = wave >> 2;               // encoder/prologue partition
  const int uw   = wave & 3;
  const int uP   = (uw << 6) | l;
  const int k4b  = kq << 4;
  const int bA   = tid >> 8;                // encoder P2 partition
  const int uA   = tid & 255;

  const int g    = blockIdx.x & 127;        // pair id
  const int H    = blockIdx.x >> 7;         // half: 0 = lo, 1 = hi
  const int b0   = g << 2;
  const int bG   = b0 + bA;
  const int ubase = H << 7;                 // owned u range [ubase, ubase+128)
  const int pbase = ubase ^ 128;            // partner's u base
  const int sbase = H << 7;                 // owned s range

  const v4f* encW4  = (const v4f*)((char*)ws + WS_ENCW4_OFF);
  const v4f* decWi4 = (const v4f*)((char*)ws + WS_DECWI4_OFF);
  const v4f* decWh4 = (const v4f*)((char*)ws + WS_DECWH4_OFF);
  v4f* encK4 = (v4f*)((char*)ws + WS_ENCK4_OFF);

  u64* hxAll  = (u64*)((char*)ws + WS_HX_OFF);
  u64* hxMe   = hxAll + (size_t)g * 1024 + (size_t)H * 512;
  u64* hxYo   = hxAll + (size_t)g * 1024 + (size_t)(1 - H) * 512;
  u64* amxAll = (u64*)((char*)ws + WS_AMX_OFF);
  u64* amxMe  = amxAll + (size_t)g * 16 + (size_t)H * 8;
  u64* amxYo  = amxAll + (size_t)g * 16 + (size_t)(1 - H) * 8;

  __shared__ __align__(16) float hsF[2][1024];   // h dbuf: [buf][b*256+u]
  __shared__ __align__(16) v4f dinV[256];        // dec_in [b][64 k4]
  __shared__ __align__(16) v4f red[17][256];     // partials; row 16 = LDS pad
  __shared__ unsigned char maskC[4][128];        // own s-half mask
  __shared__ float partV[4][2];
  __shared__ int   partI[4][2];
  __shared__ float oVs[4]; __shared__ int oIs[4];   // own half combined
  __shared__ float eV2[4][2]; __shared__ int eI2[4][2];  // partner wave partials

  // ---- encoder activation constants (keyed by uA) ----
  const float ebi_ = eBi[uA] + eBh[uA];
  const float ebf_ = eBi[256 + uA] + eBh[256 + uA];
  const float ebg_ = eBi[512 + uA] + eBh[512 + uA];
  const float ebo_ = eBi[768 + uA] + eBh[768 + uA];
  const float wxi0 = eWi[2 * uA], wxi1 = eWi[2 * uA + 1];
  const float wxf0 = eWi[2 * (256 + uA)], wxf1 = eWi[2 * (256 + uA) + 1];
  const float wxg0 = eWi[2 * (512 + uA)], wxg1 = eWi[2 * (512 + uA) + 1];
  const float wxo0 = eWi[2 * (768 + uA)], wxo1 = eWi[2 * (768 + uA) + 1];

  hsF[0][tid] = 0.f;
  __syncthreads();

  float c = 0.f;
  int p = 0;

  // ---------------- encoder: 256 steps (R10-exact, redundant per pair) ------
  for (int t = 0; t < 256; ++t) {
    v4f a0 = (v4f)0.f, a1 = (v4f)0.f, a2 = (v4f)0.f, a3 = (v4f)0.f;
    const v4f* Wp = encW4 + uP;
    const v4f* hq = (const v4f*)&hsF[p][0];
#pragma unroll 2
    for (int kk = 0; kk < 16; ++kk) {
      const int k4 = k4b + kk;
      const v4f w0 = Wp[(k4 * 4 + 0) << 8];
      const v4f w1 = Wp[(k4 * 4 + 1) << 8];
      const v4f w2 = Wp[(k4 * 4 + 2) << 8];
      const v4f w3 = Wp[(k4 * 4 + 3) << 8];
      const v4f h0 = hq[k4];
      const v4f h1 = hq[64 + k4];
      const v4f h2 = hq[128 + k4];
      const v4f h3 = hq[192 + k4];
      a0 += w0 * h0.x + w1 * h0.y + w2 * h0.z + w3 * h0.w;
      a1 += w0 * h1.x + w1 * h1.y + w2 * h1.z + w3 * h1.w;
      a2 += w0 * h2.x + w1 * h2.y + w2 * h2.z + w3 * h2.w;
      a3 += w0 * h3.x + w1 * h3.y + w2 * h3.z + w3 * h3.w;
    }
    red[(kq << 2) | 0][uP] = a0;
    red[(kq << 2) | 1][uP] = a1;
    red[(kq << 2) | 2][uP] = a2;
    red[(kq << 2) | 3][uP] = a3;
    __syncthreads();
    const v4f gv = red[bA][uA] + red[4 + bA][uA] + red[8 + bA][uA] + red[12 + bA][uA];
    const float2 xv = *(const float2*)(inp + (((bG) << 8) + t) * 2);
    const float ai = gv.x + ebi_ + wxi0 * xv.x + wxi1 * xv.y;
    const float af = gv.y + ebf_ + wxf0 * xv.x + wxf1 * xv.y;
    const float ag = gv.z + ebg_ + wxg0 * xv.x + wxg1 * xv.y;
    const float ao = gv.w + ebo_ + wxo0 * xv.x + wxo1 * xv.y;
    const float iv = sigm(ai), fv = sigm(af), gva = tanhf(ag), ov = sigm(ao);
    c = fv * c + iv * gva;
    const float hn = ov * tanhf(c);
    hsF[p ^ 1][(bA << 8) | uA] = hn;
    ((float*)encK4)[(((bG << 6) + (uA >> 2)) << 10) + (t << 2) + (uA & 3)] = hn;
    __syncthreads();
    p ^= 1;
  }

  // ---------------- decoder setup: c handoff to split mapping ----------------
  float* creg = (float*)&red[0][0];
  creg[(bA << 8) | uA] = c;
  const int isP2 = tid < 512;
  const int bD = tid >> 7;                  // 0..3   (valid if isP2)
  const int uL = tid & 127;
  const int uD = ubase | uL;                // owned global u
  __syncthreads();
  float cD = 0.f, dbi2 = 0.f, dbf2 = 0.f, dbg2 = 0.f, dbo2 = 0.f;
  if (isP2) {
    cD = creg[(bD << 8) | uD];
    dbi2 = dBi[uD] + dBh[uD];
    dbf2 = dBi[256 + uD] + dBh[256 + uD];
    dbg2 = dBi[512 + uD] + dBh[512 + uD];
    dbo2 = dBi[768 + uD] + dBh[768 + uD];
  }
  // attn identity (valid for wave >= 8)
  const int aw  = wave - 8;
  const int bAt = aw >> 1;
  const int sL  = ((aw & 1) << 6) | l;
  const int sG  = sbase | sL;
  const int bGt = b0 + bAt;
  if (wave >= 8) maskC[bAt][sL] = 0;
  // Wh identity (valid for wave < 8)
  const int kqD  = wave >> 1;
  const int k4bD = kqD << 4;
  const int uPD  = ubase | ((wave & 1) << 6) | l;
  // Wi gate-split identity (all 16 waves): (kq, gate-pair, u-half-bit)
  const int kqW  = wave >> 2;
  const int k4bW = kqW << 4;
  const int gp   = (wave >> 1) & 1;         // 0: gates i,f  1: gates g,o
  const int uW   = ubase | ((wave & 1) << 6) | l;
  const float NEG_INF = __int_as_float((int)0xff800000);
  __syncthreads();                           // creg consumed; red free

  // ---- prologue: LSTM step 0 (din=0, Wi exact-0 skipped). Wh redundant
  //      16-wave full-u (identical values in both blocks); P2 split. ----
  {
    v4f a0 = (v4f)0.f, a1 = (v4f)0.f, a2 = (v4f)0.f, a3 = (v4f)0.f;
    const v4f* Wh = decWh4 + uP;
    const v4f* hq = (const v4f*)&hsF[p][0];
#pragma unroll 2
    for (int kk = 0; kk < 16; ++kk) {
      const int k4 = k4b + kk;
      const v4f w0 = Wh[(k4 * 4 + 0) << 8];
      const v4f w1 = Wh[(k4 * 4 + 1) << 8];
      const v4f w2 = Wh[(k4 * 4 + 2) << 8];
      const v4f w3 = Wh[(k4 * 4 + 3) << 8];
      const v4f h0 = hq[k4];
      const v4f h1 = hq[64 + k4];
      const v4f h2 = hq[128 + k4];
      const v4f h3 = hq[192 + k4];
      a0 += w0 * h0.x + w1 * h0.y + w2 * h0.z + w3 * h0.w;
      a1 += w0 * h1.x + w1 * h1.y + w2 * h1.z + w3 * h1.w;
      a2 += w0 * h2.x + w1 * h2.y + w2 * h2.z + w3 * h2.w;
      a3 += w0 * h3.x + w1 * h3.y + w2 * h3.z + w3 * h3.w;
    }
    red[(kq << 2) | 0][uP] = a0;
    red[(kq << 2) | 1][uP] = a1;
    red[(kq << 2) | 2][uP] = a2;
    red[(kq << 2) | 3][uP] = a3;
    __syncthreads();
    if (isP2) {
      const v4f gv = red[bD][uD] + red[4 + bD][uD] + red[8 + bD][uD] + red[12 + bD][uD];
      const float iv = sigm(gv.x + dbi2), fv = sigm(gv.y + dbf2);
      const float gva = tanhf(gv.z + dbg2), ov = sigm(gv.w + dbo2);
      cD = fv * cD + iv * gva;
      const float hn = ov * tanhf(cD);
      hsF[p ^ 1][(bD << 8) | uD] = hn;
      atomicExch(&hxMe[(bD << 7) | uL], pk(0xA5000000u, __float_as_uint(hn)));
      const unsigned pw = spinrd(&hxYo[(bD << 7) | uL], 0xA5000000u);
      hsF[p ^ 1][(bD << 8) | pbase | uL] = __uint_as_float(pw);
    }
    __syncthreads();
    p ^= 1;                                   // hsF[p] = full h_0
  }

  // winner fold: max val, min idx on ties — order-independent semantics
#define WINNER(B, WI) { float _wv = oVs[B]; int _wi = oIs[B];                 \
    { const float _e = eV2[B][0]; const int _i = eI2[B][0];                   \
      if (_e > _wv || (_e == _wv && _i < _wi)) { _wv = _e; _wi = _i; } }      \
    { const float _e = eV2[B][1]; const int _i = eI2[B][1];                   \
      if (_e > _wv || (_e == _wv && _i < _wi)) { _wv = _e; _wi = _i; } }      \
    WI = _wi; }

  for (int t = 0; t < 256; ++t) {
    const unsigned tagA9 = (unsigned)t + 1u;  // 1..256, never 0
    const unsigned tagH = 0xA5000002u + 2u * (unsigned)t;
    const v4f* hq = (const v4f*)&hsF[p][0];

    // ==== phase X: waves 0-7 Wh·h_t (u-half) ∥ waves 8-15 attention(t) ====
    if (wave < 8) {
      v4f a0 = (v4f)0.f, a1 = (v4f)0.f, a2 = (v4f)0.f, a3 = (v4f)0.f;
      const v4f* Wh = decWh4 + uPD;
#pragma unroll 2
      for (int kk = 0; kk < 16; ++kk) {
        const int k4 = k4bD + kk;
        const v4f w0 = Wh[(k4 * 4 + 0) << 8];
        const v4f w1 = Wh[(k4 * 4 + 1) << 8];
        const v4f w2 = Wh[(k4 * 4 + 2) << 8];
        const v4f w3 = Wh[(k4 * 4 + 3) << 8];
        const v4f h0 = hq[k4];
        const v4f h1 = hq[64 + k4];
        const v4f h2 = hq[128 + k4];
        const v4f h3 = hq[192 + k4];
        a0 += w0 * h0.x + w1 * h0.y + w2 * h0.z + w3 * h0.w;
        a1 += w0 * h1.x + w1 * h1.y + w2 * h1.z + w3 * h1.w;
        a2 += w0 * h2.x + w1 * h2.y + w2 * h2.z + w3 * h2.w;
        a3 += w0 * h3.x + w1 * h3.y + w2 * h3.z + w3 * h3.w;
      }
      red[(kqD << 2) | 0][uPD] = a0;
      red[(kqD << 2) | 1][uPD] = a1;
      red[(kqD << 2) | 2][uPD] = a2;
      red[(kqD << 2) | 3][uPD] = a3;
    } else {
      const int masked = maskC[bAt][sL];
      float sc = 0.f;
      if (!masked) {
        const v4f* E = encK4 + (bGt << 14) + sG;
        const v4f* hq2 = hq + (bAt << 6);
#pragma unroll 4
        for (int k4 = 0; k4 < 64; ++k4) {
          const v4f ev = E[k4 << 8];
          const v4f hv = hq2[k4];
          sc += ev.x * hv.x + ev.y * hv.y + ev.z * hv.z + ev.w * hv.w;
        }
      }
      unsigned bits;
      {
        unsigned kk0 = 0u, kk1 = (unsigned)t;
        tf2(0u, 42u, kk0, kk1);
        unsigned y0 = 0u, y1 = (unsigned)((bGt << 8) + sG);
        tf2(kk0, kk1, y0, y1);
        bits = y0 ^ y1;
      }
      const float fr = __uint_as_float((bits >> 9) | 0x3f800000u) - 1.0f;
      const float uu = (fr > 0.f) ? fr : 1.17549435e-38f;
      const float gum = -logf(-logf(uu));
      float bv = masked ? NEG_INF : (sc + gum);
      int bi = sG;
#pragma unroll
      for (int off = 32; off; off >>= 1) {
        const float ov2 = __shfl_xor(bv, off, 64);
        const int oi2 = __shfl_xor(bi, off, 64);
        if (ov2 > bv || (ov2 == bv && oi2 < bi)) { bv = ov2; bi = oi2; }
      }
      if (l == 0) {
        partV[bAt][aw & 1] = bv; partI[bAt][aw & 1] = bi;
        // EARLY publish: in flight while Wh waves finish their stream
        atomicExch(&amxMe[(bAt << 1) | (aw & 1)], pk49(tagA9, bv, bi));
      }
    }
    __syncthreads();                          // S1: red-Wh + partials ready

    // ==== own combine (tid 0-3); spin partner per-wave words (tid 64-71) ====
    if (tid < 4) {
      float v0 = partV[tid][0]; int i0 = partI[tid][0];
      const float v1 = partV[tid][1];
      if (v1 > v0) { v0 = v1; i0 = partI[tid][1]; }   // strict >: lower s kept
      oVs[tid] = v0; oIs[tid] = i0;
    }
    if (tid >= 64 && tid < 72) {
      const int j = tid - 64;                 // (batch<<1)|wv
      const u64 w = spinrd49(&amxYo[j], tagA9);
      eV2[j >> 1][j & 1] = __uint_as_float((unsigned)(w >> 8));
      eI2[j >> 1][j & 1] = (int)(w & 0xFF);
    }
    __syncthreads();                          // S2: both halves' results ready

    // ==== winner, mask, out, din staging ====
    if (wave >= 8) {
      int wi; WINNER(bAt, wi);
      if (sG == wi) maskC[bAt][sL] = 1;
    }
    if (H == 0 && tid < 4) {
      int wi; WINNER(tid, wi);
      out[((b0 + tid) << 8) + t] = wi;
    }
    if (tid < 256) {
      const int bb = tid >> 6, k4s = tid & 63;
      int wi; WINNER(bb, wi);
      dinV[tid] = encK4[((((b0 + bb) << 6) | k4s) << 8) + wi];
    }
    __syncthreads();                          // S3: din/mask ready

    if (t == 255) break;                      // last index emitted

    // ==== Wi·din sweep: ALL 16 waves, gate-split v2f chains (bit-exact:
    //      per-gate FLOP sequence identical to the v4f lane of R13) ====
    {
      const float* redb = (const float*)&red[0][0];
      float* redw = (float*)&red[0][0];
      const int uo = (uW << 2) | (gp << 1);          // float offset of v2f half
      v2f a0 = *(const v2f*)(redb + (((kqW << 2) | 0) << 10) + uo);
      v2f a1 = *(const v2f*)(redb + (((kqW << 2) | 1) << 10) + uo);
      v2f a2 = *(const v2f*)(redb + (((kqW << 2) | 2) << 10) + uo);
      v2f a3 = *(const v2f*)(redb + (((kqW << 2) | 3) << 10) + uo);
      const float* Wib = (const float*)decWi4;
#pragma unroll 2
      for (int kk = 0; kk < 16; ++kk) {
        const int k4 = k4bW + kk;
        const v2f w0 = *(const v2f*)(Wib + (((k4 * 4 + 0) << 8) << 2) + uo);
        const v2f w1 = *(const v2f*)(Wib + (((k4 * 4 + 1) << 8) << 2) + uo);
        const v2f w2 = *(const v2f*)(Wib + (((k4 * 4 + 2) << 8) << 2) + uo);
        const v2f w3 = *(const v2f*)(Wib + (((k4 * 4 + 3) << 8) << 2) + uo);
        const v4f d0 = dinV[k4];
        const v4f d1 = dinV[64 + k4];
        const v4f d2 = dinV[128 + k4];
        const v4f d3 = dinV[192 + k4];
        a0 += w0 * d0.x + w1 * d0.y + w2 * d0.z + w3 * d0.w;
        a1 += w0 * d1.x + w1 * d1.y + w2 * d1.z + w3 * d1.w;
        a2 += w0 * d2.x + w1 * d2.y + w2 * d2.z + w3 * d2.w;
        a3 += w0 * d3.x + w1 * d3.y + w2 * d3.z + w3 * d3.w;
      }
      *(v2f*)(redw + (((kqW << 2) | 0) << 10) + uo) = a0;
      *(v2f*)(redw + (((kqW << 2) | 1) << 10) + uo) = a1;
      *(v2f*)(redw + (((kqW << 2) | 2) << 10) + uo) = a2;
      *(v2f*)(redw + (((kqW << 2) | 3) << 10) + uo) = a3;
    }
    __syncthreads();                          // S4: full partials ready

    // ==== P2 (split) -> h_{t+1}; publish + fetch partner half ====
    if (isP2) {
      const v4f gv = red[bD][uD] + red[4 + bD][uD] + red[8 + bD][uD] + red[12 + bD][uD];
      const float iv = sigm(gv.x + dbi2), fv = sigm(gv.y + dbf2);
      const float gva = tanhf(gv.z + dbg2), ov = sigm(gv.w + dbo2);
      cD = fv * cD + iv * gva;
      const float hn = ov * tanhf(cD);
      hsF[p ^ 1][(bD << 8) | uD] = hn;
      atomicExch(&hxMe[(bD << 7) | uL], pk(tagH, __float_as_uint(hn)));
      const unsigned pw = spinrd(&hxYo[(bD << 7) | uL], tagH);
      hsF[p ^ 1][(bD << 8) | pbase | uL] = __uint_as_float(pw);
    }
    __syncthreads();                          // S5: full h_{t+1} ready
    p ^= 1;
  }
#undef WINNER
}

extern "C" void kernel_launch(void* const* d_in, const int* in_sizes, int n_in,
                              void* d_out, int out_size, void* d_ws, size_t ws_size,
                              hipStream_t stream) {
  (void)in_sizes; (void)n_in; (void)out_size;
  if (ws_size < WS_NEEDED) return;   // need ~139 MB scratch

  const float* inp = (const float*)d_in[0];
  const float* eWi = (const float*)d_in[1];
  const float* eWh = (const float*)d_in[2];
  const float* eBi = (const float*)d_in[3];
  const float* eBh = (const float*)d_in[4];
  const float* dWi = (const float*)d_in[5];
  const float* dWh = (const float*)d_in[6];
  const float* dBi = (const float*)d_in[7];
  const float* dBh = (const float*)d_in[8];
  int* out = (int*)d_out;
  float* wsf = (float*)d_ws;

  // zero the sync region every launch: fresh tags, no ABA across graph replays
  hipMemsetAsync((char*)d_ws + WS_HX_OFF, 0, WS_SYNC_BYTES, stream);
  hipLaunchKernelGGL(repack_k, dim3(256), dim3(256), 0, stream, eWh, dWi, dWh, wsf);
  hipLaunchKernelGGL(ptrnet_kernel, dim3(256), dim3(1024), 0, stream,
                     inp, eWi, eBi, eBh, dBi, dBh, out, wsf);
}

// Round 14
// 9325.610 us; speedup vs baseline: 1.0527x; 1.0185x over previous
//
#include <hip/hip_runtime.h>
#include <cstdint>
#include <cstddef>

// ============================================================================
// PointerNet: encoder LSTM (B=512,S=256,D=2,H=256) + autoregressive pointer
// decode with jax.random.categorical (threefry2x32 partitionable, key 42).
// Output: int32 indices [512][256], trajectory-exact vs JAX reference.
//
// R18 = R13 (best verified, 9294us) + EARLY argmax publish ONLY.
// R17 post-mortem: its two changes decompose cleanly via counters —
// SQ_LDS_BANK_CONFLICT 0 -> 2.5e7 was the Wi gate-split (v2f reads at
// 16B lane stride = 8-way bank conflict, inherent to the layout) costing
// ~+0.4ms; the early publish is plausible but was masked. R18 keeps ONLY
// the early publish:
//   attention wave lane0 publishes its per-wave partial (packed u64:
//   tag9|val32|idx8, tag=t+1) immediately after the shfl argmax, INSIDE
//   phase X — in flight during the Wh-wave tail, so the cross-XCD RT is
//   off the critical path. Winner = 3-way lexicographic fold (max val,
//   min idx on tie) over {own-combined, partner-w0, partner-w1} —
//   order-independent, bit-identical to R13's 2-way fold.
// Wi sweep: verbatim R13 (8 waves, v4f, conflict-free, chain from red).
// Everything else byte-for-byte R13 (absmax 0 proven).
// ============================================================================

typedef float v4f __attribute__((ext_vector_type(4)));
typedef unsigned long long u64;

#define WS_HX_OFF     0u                 // [128 g][2 H][512] u64 = 1 MB
#define WS_AMX_OFF    (1u << 20)         // [128 g][2 H][8] u64 = 16 KB
#define WS_SYNC_BYTES 0x110000u
#define WS_ENCW4_OFF  (2u << 20)         // [256 k][256 u][4 g] f32
#define WS_DECWI4_OFF (3u << 20)
#define WS_DECWH4_OFF (4u << 20)
#define WS_ENCK4_OFF  (5u << 20)         // [512 b][64 u4][256 s][4] f32
#define WS_NEEDED     ((size_t)(5u << 20) + (size_t)512 * 64 * 256 * 16)

__device__ __forceinline__ unsigned rotl32(unsigned x, int r) {
  return (x << r) | (x >> (32 - r));
}
__device__ __forceinline__ float sigm(float x) { return 1.f / (1.f + expf(-x)); }

__device__ __forceinline__ u64 pk(unsigned tag, unsigned payload) {
  return ((u64)tag << 32) | (u64)payload;
}
// argmax partial: [tag9:24][val:32][idx:8]; tag = t+1 (1..256, never 0)
__device__ __forceinline__ u64 pk49(unsigned tag9, float v, int idx) {
  return ((u64)tag9 << 40) | ((u64)__float_as_uint(v) << 8) | (u64)(idx & 0xFF);
}
// device-scope atomic read (resolves at coherence point; no stale L1/L2)
__device__ __forceinline__ unsigned spinrd(u64* p, unsigned tag) {
  u64 v = atomicAdd(p, 0ull);
  while ((unsigned)(v >> 32) != tag) {
    __builtin_amdgcn_s_sleep(2);
    v = atomicAdd(p, 0ull);
  }
  return (unsigned)v;
}
__device__ __forceinline__ u64 spinrd49(u64* p, unsigned tag9) {
  u64 v = atomicAdd(p, 0ull);
  while ((unsigned)(v >> 40) != tag9) {
    __builtin_amdgcn_s_sleep(2);
    v = atomicAdd(p, 0ull);
  }
  return v;
}

// Threefry-2x32, 20 rounds (jax._src.prng schedule) — verified exact R1-R17.
__device__ __forceinline__ void tf2(unsigned k0, unsigned k1,
                                    unsigned& x0, unsigned& x1) {
  const unsigned k2 = k0 ^ k1 ^ 0x1BD11BDAu;
  x0 += k0; x1 += k1;
  x0 += x1; x1 = rotl32(x1, 13); x1 ^= x0;
  x0 += x1; x1 = rotl32(x1, 15); x1 ^= x0;
  x0 += x1; x1 = rotl32(x1, 26); x1 ^= x0;
  x0 += x1; x1 = rotl32(x1,  6); x1 ^= x0;
  x0 += k1; x1 += k2 + 1u;
  x0 += x1; x1 = rotl32(x1, 17); x1 ^= x0;
  x0 += x1; x1 = rotl32(x1, 29); x1 ^= x0;
  x0 += x1; x1 = rotl32(x1, 16); x1 ^= x0;
  x0 += x1; x1 = rotl32(x1, 24); x1 ^= x0;
  x0 += k2; x1 += k0 + 2u;
  x0 += x1; x1 = rotl32(x1, 13); x1 ^= x0;
  x0 += x1; x1 = rotl32(x1, 15); x1 ^= x0;
  x0 += x1; x1 = rotl32(x1, 26); x1 ^= x0;
  x0 += x1; x1 = rotl32(x1,  6); x1 ^= x0;
  x0 += k0; x1 += k1 + 3u;
  x0 += x1; x1 = rotl32(x1, 17); x1 ^= x0;
  x0 += x1; x1 = rotl32(x1, 29); x1 ^= x0;
  x0 += x1; x1 = rotl32(x1, 16); x1 ^= x0;
  x0 += x1; x1 = rotl32(x1, 24); x1 ^= x0;
  x0 += k1; x1 += k2 + 4u;
  x0 += x1; x1 = rotl32(x1, 13); x1 ^= x0;
  x0 += x1; x1 = rotl32(x1, 15); x1 ^= x0;
  x0 += x1; x1 = rotl32(x1, 26); x1 ^= x0;
  x0 += x1; x1 = rotl32(x1,  6); x1 ^= x0;
  x0 += k2; x1 += k0 + 5u;
}

// Repack W [1024 rows][256 k] row-major -> [k][u][gate] (float4 per (k,u)).
__global__ void repack_k(const float* __restrict__ eWh,
                         const float* __restrict__ dWi,
                         const float* __restrict__ dWh,
                         float* __restrict__ ws) {
  float* encW4 = (float*)((char*)ws + WS_ENCW4_OFF);
  float* decWi4 = (float*)((char*)ws + WS_DECWI4_OFF);
  float* decWh4 = (float*)((char*)ws + WS_DECWH4_OFF);
  const int n = blockIdx.x * blockDim.x + threadIdx.x;   // 65536 = 256k x 256u
  if (n >= 65536) return;
  const int k = n >> 8, u = n & 255;
#pragma unroll
  for (int g = 0; g < 4; ++g) {
    const int src = ((g << 8) + u) * 256 + k;
    const int dst = (n << 2) + g;
    encW4[dst] = eWh[src];
    decWi4[dst] = dWi[src];
    decWh4[dst] = dWh[src];
  }
}

__global__ void __launch_bounds__(1024)
ptrnet_kernel(const float* __restrict__ inp,    // [512][256][2]
              const float* __restrict__ eWi,    // [1024][2]
              const float* __restrict__ eBi, const float* __restrict__ eBh,
              const float* __restrict__ dBi, const float* __restrict__ dBh,
              int* __restrict__ out,            // [512][256]
              float* __restrict__ ws) {
  const int tid  = threadIdx.x;
  const int wave = tid >> 6, l = tid & 63;
  const int kq   = wave >> 2;               // encoder/prologue partition
  const int uw   = wave & 3;
  const int uP   = (uw << 6) | l;
  const int k4b  = kq << 4;
  const int bA   = tid >> 8;                // encoder P2 partition
  const int uA   = tid & 255;

  const int g    = blockIdx.x & 127;        // pair id
  const int H    = blockIdx.x >> 7;         // half: 0 = lo, 1 = hi
  const int b0   = g << 2;
  const int bG   = b0 + bA;
  const int ubase = H << 7;                 // owned u range [ubase, ubase+128)
  const int pbase = ubase ^ 128;            // partner's u base
  const int sbase = H << 7;                 // owned s range

  const v4f* encW4  = (const v4f*)((char*)ws + WS_ENCW4_OFF);
  const v4f* decWi4 = (const v4f*)((char*)ws + WS_DECWI4_OFF);
  const v4f* decWh4 = (const v4f*)((char*)ws + WS_DECWH4_OFF);
  v4f* encK4 = (v4f*)((char*)ws + WS_ENCK4_OFF);

  u64* hxAll  = (u64*)((char*)ws + WS_HX_OFF);
  u64* hxMe   = hxAll + (size_t)g * 1024 + (size_t)H * 512;
  u64* hxYo   = hxAll + (size_t)g * 1024 + (size_t)(1 - H) * 512;
  u64* amxAll = (u64*)((char*)ws + WS_AMX_OFF);
  u64* amxMe  = amxAll + (size_t)g * 16 + (size_t)H * 8;
  u64* amxYo  = amxAll + (size_t)g * 16 + (size_t)(1 - H) * 8;

  __shared__ __align__(16) float hsF[2][1024];   // h dbuf: [buf][b*256+u]
  __shared__ __align__(16) v4f dinV[256];        // dec_in [b][64 k4]
  __shared__ __align__(16) v4f red[17][256];     // partials; row 16 = LDS pad
  __shared__ unsigned char maskC[4][128];        // own s-half mask
  __shared__ float partV[4][2];
  __shared__ int   partI[4][2];
  __shared__ float oVs[4]; __shared__ int oIs[4];   // own half combined
  __shared__ float eV2[4][2]; __shared__ int eI2[4][2];  // partner wave partials

  // ---- encoder activation constants (keyed by uA) ----
  const float ebi_ = eBi[uA] + eBh[uA];
  const float ebf_ = eBi[256 + uA] + eBh[256 + uA];
  const float ebg_ = eBi[512 + uA] + eBh[512 + uA];
  const float ebo_ = eBi[768 + uA] + eBh[768 + uA];
  const float wxi0 = eWi[2 * uA], wxi1 = eWi[2 * uA + 1];
  const float wxf0 = eWi[2 * (256 + uA)], wxf1 = eWi[2 * (256 + uA) + 1];
  const float wxg0 = eWi[2 * (512 + uA)], wxg1 = eWi[2 * (512 + uA) + 1];
  const float wxo0 = eWi[2 * (768 + uA)], wxo1 = eWi[2 * (768 + uA) + 1];

  hsF[0][tid] = 0.f;
  __syncthreads();

  float c = 0.f;
  int p = 0;

  // ---------------- encoder: 256 steps (R10-exact, redundant per pair) ------
  for (int t = 0; t < 256; ++t) {
    v4f a0 = (v4f)0.f, a1 = (v4f)0.f, a2 = (v4f)0.f, a3 = (v4f)0.f;
    const v4f* Wp = encW4 + uP;
    const v4f* hq = (const v4f*)&hsF[p][0];
#pragma unroll 2
    for (int kk = 0; kk < 16; ++kk) {
      const int k4 = k4b + kk;
      const v4f w0 = Wp[(k4 * 4 + 0) << 8];
      const v4f w1 = Wp[(k4 * 4 + 1) << 8];
      const v4f w2 = Wp[(k4 * 4 + 2) << 8];
      const v4f w3 = Wp[(k4 * 4 + 3) << 8];
      const v4f h0 = hq[k4];
      const v4f h1 = hq[64 + k4];
      const v4f h2 = hq[128 + k4];
      const v4f h3 = hq[192 + k4];
      a0 += w0 * h0.x + w1 * h0.y + w2 * h0.z + w3 * h0.w;
      a1 += w0 * h1.x + w1 * h1.y + w2 * h1.z + w3 * h1.w;
      a2 += w0 * h2.x + w1 * h2.y + w2 * h2.z + w3 * h2.w;
      a3 += w0 * h3.x + w1 * h3.y + w2 * h3.z + w3 * h3.w;
    }
    red[(kq << 2) | 0][uP] = a0;
    red[(kq << 2) | 1][uP] = a1;
    red[(kq << 2) | 2][uP] = a2;
    red[(kq << 2) | 3][uP] = a3;
    __syncthreads();
    const v4f gv = red[bA][uA] + red[4 + bA][uA] + red[8 + bA][uA] + red[12 + bA][uA];
    const float2 xv = *(const float2*)(inp + (((bG) << 8) + t) * 2);
    const float ai = gv.x + ebi_ + wxi0 * xv.x + wxi1 * xv.y;
    const float af = gv.y + ebf_ + wxf0 * xv.x + wxf1 * xv.y;
    const float ag = gv.z + ebg_ + wxg0 * xv.x + wxg1 * xv.y;
    const float ao = gv.w + ebo_ + wxo0 * xv.x + wxo1 * xv.y;
    const float iv = sigm(ai), fv = sigm(af), gva = tanhf(ag), ov = sigm(ao);
    c = fv * c + iv * gva;
    const float hn = ov * tanhf(c);
    hsF[p ^ 1][(bA << 8) | uA] = hn;
    ((float*)encK4)[(((bG << 6) + (uA >> 2)) << 10) + (t << 2) + (uA & 3)] = hn;
    __syncthreads();
    p ^= 1;
  }

  // ---------------- decoder setup: c handoff to split mapping ----------------
  float* creg = (float*)&red[0][0];
  creg[(bA << 8) | uA] = c;
  const int isP2 = tid < 512;
  const int bD = tid >> 7;                  // 0..3   (valid if isP2)
  const int uL = tid & 127;
  const int uD = ubase | uL;                // owned global u
  __syncthreads();
  float cD = 0.f, dbi2 = 0.f, dbf2 = 0.f, dbg2 = 0.f, dbo2 = 0.f;
  if (isP2) {
    cD = creg[(bD << 8) | uD];
    dbi2 = dBi[uD] + dBh[uD];
    dbf2 = dBi[256 + uD] + dBh[256 + uD];
    dbg2 = dBi[512 + uD] + dBh[512 + uD];
    dbo2 = dBi[768 + uD] + dBh[768 + uD];
  }
  // attn identity (valid for wave >= 8)
  const int aw  = wave - 8;
  const int bAt = aw >> 1;
  const int sL  = ((aw & 1) << 6) | l;
  const int sG  = sbase | sL;
  const int bGt = b0 + bAt;
  if (wave >= 8) maskC[bAt][sL] = 0;
  // Wh/Wi identity (valid for wave < 8)
  const int kqD  = wave >> 1;
  const int k4bD = kqD << 4;
  const int uPD  = ubase | ((wave & 1) << 6) | l;
  const float NEG_INF = __int_as_float((int)0xff800000);
  __syncthreads();                           // creg consumed; red free

  // ---- prologue: LSTM step 0 (din=0, Wi exact-0 skipped). Wh redundant
  //      16-wave full-u (identical values in both blocks); P2 split. ----
  {
    v4f a0 = (v4f)0.f, a1 = (v4f)0.f, a2 = (v4f)0.f, a3 = (v4f)0.f;
    const v4f* Wh = decWh4 + uP;
    const v4f* hq = (const v4f*)&hsF[p][0];
#pragma unroll 2
    for (int kk = 0; kk < 16; ++kk) {
      const int k4 = k4b + kk;
      const v4f w0 = Wh[(k4 * 4 + 0) << 8];
      const v4f w1 = Wh[(k4 * 4 + 1) << 8];
      const v4f w2 = Wh[(k4 * 4 + 2) << 8];
      const v4f w3 = Wh[(k4 * 4 + 3) << 8];
      const v4f h0 = hq[k4];
      const v4f h1 = hq[64 + k4];
      const v4f h2 = hq[128 + k4];
      const v4f h3 = hq[192 + k4];
      a0 += w0 * h0.x + w1 * h0.y + w2 * h0.z + w3 * h0.w;
      a1 += w0 * h1.x + w1 * h1.y + w2 * h1.z + w3 * h1.w;
      a2 += w0 * h2.x + w1 * h2.y + w2 * h2.z + w3 * h2.w;
      a3 += w0 * h3.x + w1 * h3.y + w2 * h3.z + w3 * h3.w;
    }
    red[(kq << 2) | 0][uP] = a0;
    red[(kq << 2) | 1][uP] = a1;
    red[(kq << 2) | 2][uP] = a2;
    red[(kq << 2) | 3][uP] = a3;
    __syncthreads();
    if (isP2) {
      const v4f gv = red[bD][uD] + red[4 + bD][uD] + red[8 + bD][uD] + red[12 + bD][uD];
      const float iv = sigm(gv.x + dbi2), fv = sigm(gv.y + dbf2);
      const float gva = tanhf(gv.z + dbg2), ov = sigm(gv.w + dbo2);
      cD = fv * cD + iv * gva;
      const float hn = ov * tanhf(cD);
      hsF[p ^ 1][(bD << 8) | uD] = hn;
      atomicExch(&hxMe[(bD << 7) | uL], pk(0xA5000000u, __float_as_uint(hn)));
      const unsigned pw = spinrd(&hxYo[(bD << 7) | uL], 0xA5000000u);
      hsF[p ^ 1][(bD << 8) | pbase | uL] = __uint_as_float(pw);
    }
    __syncthreads();
    p ^= 1;                                   // hsF[p] = full h_0
  }

  // winner fold: max val, min idx on ties — order-independent semantics
#define WINNER(B, WI) { float _wv = oVs[B]; int _wi = oIs[B];                 \
    { const float _e = eV2[B][0]; const int _i = eI2[B][0];                   \
      if (_e > _wv || (_e == _wv && _i < _wi)) { _wv = _e; _wi = _i; } }      \
    { const float _e = eV2[B][1]; const int _i = eI2[B][1];                   \
      if (_e > _wv || (_e == _wv && _i < _wi)) { _wv = _e; _wi = _i; } }      \
    WI = _wi; }

  for (int t = 0; t < 256; ++t) {
    const unsigned tagA9 = (unsigned)t + 1u;  // 1..256, never 0
    const unsigned tagH = 0xA5000002u + 2u * (unsigned)t;
    const v4f* hq = (const v4f*)&hsF[p][0];

    // ==== phase X: waves 0-7 Wh·h_t (u-half) ∥ waves 8-15 attention(t) ====
    if (wave < 8) {
      v4f a0 = (v4f)0.f, a1 = (v4f)0.f, a2 = (v4f)0.f, a3 = (v4f)0.f;
      const v4f* Wh = decWh4 + uPD;
#pragma unroll 2
      for (int kk = 0; kk < 16; ++kk) {
        const int k4 = k4bD + kk;
        const v4f w0 = Wh[(k4 * 4 + 0) << 8];
        const v4f w1 = Wh[(k4 * 4 + 1) << 8];
        const v4f w2 = Wh[(k4 * 4 + 2) << 8];
        const v4f w3 = Wh[(k4 * 4 + 3) << 8];
        const v4f h0 = hq[k4];
        const v4f h1 = hq[64 + k4];
        const v4f h2 = hq[128 + k4];
        const v4f h3 = hq[192 + k4];
        a0 += w0 * h0.x + w1 * h0.y + w2 * h0.z + w3 * h0.w;
        a1 += w0 * h1.x + w1 * h1.y + w2 * h1.z + w3 * h1.w;
        a2 += w0 * h2.x + w1 * h2.y + w2 * h2.z + w3 * h2.w;
        a3 += w0 * h3.x + w1 * h3.y + w2 * h3.z + w3 * h3.w;
      }
      red[(kqD << 2) | 0][uPD] = a0;
      red[(kqD << 2) | 1][uPD] = a1;
      red[(kqD << 2) | 2][uPD] = a2;
      red[(kqD << 2) | 3][uPD] = a3;
    } else {
      const int masked = maskC[bAt][sL];
      float sc = 0.f;
      if (!masked) {
        const v4f* E = encK4 + (bGt << 14) + sG;
        const v4f* hq2 = hq + (bAt << 6);
#pragma unroll 4
        for (int k4 = 0; k4 < 64; ++k4) {
          const v4f ev = E[k4 << 8];
          const v4f hv = hq2[k4];
          sc += ev.x * hv.x + ev.y * hv.y + ev.z * hv.z + ev.w * hv.w;
        }
      }
      unsigned bits;
      {
        unsigned kk0 = 0u, kk1 = (unsigned)t;
        tf2(0u, 42u, kk0, kk1);
        unsigned y0 = 0u, y1 = (unsigned)((bGt << 8) + sG);
        tf2(kk0, kk1, y0, y1);
        bits = y0 ^ y1;
      }
      const float fr = __uint_as_float((bits >> 9) | 0x3f800000u) - 1.0f;
      const float uu = (fr > 0.f) ? fr : 1.17549435e-38f;
      const float gum = -logf(-logf(uu));
      float bv = masked ? NEG_INF : (sc + gum);
      int bi = sG;
#pragma unroll
      for (int off = 32; off; off >>= 1) {
        const float ov2 = __shfl_xor(bv, off, 64);
        const int oi2 = __shfl_xor(bi, off, 64);
        if (ov2 > bv || (ov2 == bv && oi2 < bi)) { bv = ov2; bi = oi2; }
      }
      if (l == 0) {
        partV[bAt][aw & 1] = bv; partI[bAt][aw & 1] = bi;
        // EARLY publish: in flight while Wh waves finish their stream
        atomicExch(&amxMe[(bAt << 1) | (aw & 1)], pk49(tagA9, bv, bi));
      }
    }
    __syncthreads();                          // S1: red-Wh + partials ready

    // ==== own combine (tid 0-3); spin partner per-wave words (tid 64-71) ====
    if (tid < 4) {
      float v0 = partV[tid][0]; int i0 = partI[tid][0];
      const float v1 = partV[tid][1];
      if (v1 > v0) { v0 = v1; i0 = partI[tid][1]; }   // strict >: lower s kept
      oVs[tid] = v0; oIs[tid] = i0;
    }
    if (tid >= 64 && tid < 72) {
      const int j = tid - 64;                 // (batch<<1)|wv
      const u64 w = spinrd49(&amxYo[j], tagA9);
      eV2[j >> 1][j & 1] = __uint_as_float((unsigned)(w >> 8));
      eI2[j >> 1][j & 1] = (int)(w & 0xFF);
    }
    __syncthreads();                          // S2: both halves' results ready

    // ==== winner, mask, out, din staging ====
    if (wave >= 8) {
      int wi; WINNER(bAt, wi);
      if (sG == wi) maskC[bAt][sL] = 1;
    }
    if (H == 0 && tid < 4) {
      int wi; WINNER(tid, wi);
      out[((b0 + tid) << 8) + t] = wi;
    }
    if (tid < 256) {
      const int bb = tid >> 6, k4s = tid & 63;
      int wi; WINNER(bb, wi);
      dinV[tid] = encK4[((((b0 + bb) << 6) | k4s) << 8) + wi];
    }
    __syncthreads();                          // S3: din/mask ready

    if (t == 255) break;                      // last index emitted

    // ==== Wi·din sweep (waves 0-7, continue chain from red — lossless) ====
    if (wave < 8) {
      v4f a0 = red[(kqD << 2) | 0][uPD];
      v4f a1 = red[(kqD << 2) | 1][uPD];
      v4f a2 = red[(kqD << 2) | 2][uPD];
      v4f a3 = red[(kqD << 2) | 3][uPD];
      const v4f* Wi = decWi4 + uPD;
#pragma unroll 2
      for (int kk = 0; kk < 16; ++kk) {
        const int k4 = k4bD + kk;
        const v4f w0 = Wi[(k4 * 4 + 0) << 8];
        const v4f w1 = Wi[(k4 * 4 + 1) << 8];
        const v4f w2 = Wi[(k4 * 4 + 2) << 8];
        const v4f w3 = Wi[(k4 * 4 + 3) << 8];
        const v4f d0 = dinV[k4];
        const v4f d1 = dinV[64 + k4];
        const v4f d2 = dinV[128 + k4];
        const v4f d3 = dinV[192 + k4];
        a0 += w0 * d0.x + w1 * d0.y + w2 * d0.z + w3 * d0.w;
        a1 += w0 * d1.x + w1 * d1.y + w2 * d1.z + w3 * d1.w;
        a2 += w0 * d2.x + w1 * d2.y + w2 * d2.z + w3 * d2.w;
        a3 += w0 * d3.x + w1 * d3.y + w2 * d3.z + w3 * d3.w;
      }
      red[(kqD << 2) | 0][uPD] = a0;
      red[(kqD << 2) | 1][uPD] = a1;
      red[(kqD << 2) | 2][uPD] = a2;
      red[(kqD << 2) | 3][uPD] = a3;
    }
    __syncthreads();                          // S4: full partials ready

    // ==== P2 (split) -> h_{t+1}; publish + fetch partner half ====
    if (isP2) {
      const v4f gv = red[bD][uD] + red[4 + bD][uD] + red[8 + bD][uD] + red[12 + bD][uD];
      const float iv = sigm(gv.x + dbi2), fv = sigm(gv.y + dbf2);
      const float gva = tanhf(gv.z + dbg2), ov = sigm(gv.w + dbo2);
      cD = fv * cD + iv * gva;
      const float hn = ov * tanhf(cD);
      hsF[p ^ 1][(bD << 8) | uD] = hn;
      atomicExch(&hxMe[(bD << 7) | uL], pk(tagH, __float_as_uint(hn)));
      const unsigned pw = spinrd(&hxYo[(bD << 7) | uL], tagH);
      hsF[p ^ 1][(bD << 8) | pbase | uL] = __uint_as_float(pw);
    }
    __syncthreads();                          // S5: full h_{t+1} ready
    p ^= 1;
  }
#undef WINNER
}

extern "C" void kernel_launch(void* const* d_in, const int* in_sizes, int n_in,
                              void* d_out, int out_size, void* d_ws, size_t ws_size,
                              hipStream_t stream) {
  (void)in_sizes; (void)n_in; (void)out_size;
  if (ws_size < WS_NEEDED) return;   // need ~139 MB scratch

  const float* inp = (const float*)d_in[0];
  const float* eWi = (const float*)d_in[1];
  const float* eWh = (const float*)d_in[2];
  const float* eBi = (const float*)d_in[3];
  const float* eBh = (const float*)d_in[4];
  const float* dWi = (const float*)d_in[5];
  const float* dWh = (const float*)d_in[6];
  const float* dBi = (const float*)d_in[7];
  const float* dBh = (const float*)d_in[8];
  int* out = (int*)d_out;
  float* wsf = (float*)d_ws;

  // zero the sync region every launch: fresh tags, no ABA across graph replays
  hipMemsetAsync((char*)d_ws + WS_HX_OFF, 0, WS_SYNC_BYTES, stream);
  hipLaunchKernelGGL(repack_k, dim3(256), dim3(256), 0, stream, eWh, dWi, dWh, wsf);
  hipLaunchKernelGGL(ptrnet_kernel, dim3(256), dim3(1024), 0, stream,
                     inp, eWi, eBi, eBh, dBi, dBh, out, wsf);
}